// Round 1
// baseline (5217.617 us; speedup 1.0000x reference)
//
#include <hip/hip_runtime.h>

#define Bb 4
#define Ss 1024
#define Dd 1024
#define Hh 16
#define HDd 64
#define FFf 2048
#define HIDh 4096
#define NTOK (Bb*Ss)

__device__ __forceinline__ float gelu_f(float x) {
  return 0.5f * x * (1.0f + erff(x * 0.70710678118654752f));
}

// ---------------- fp32 SGEMM: C[M,N] = A[M,K] @ W[K,N] + bias (+gelu) -------
// 128x128 tile, BK=8, 256 threads, 2x2 of 4x4 micro-tiles per thread.
template<int GELU>
__global__ __launch_bounds__(256)
void gemm_k(const float* __restrict__ A, const float* __restrict__ W,
            const float* __restrict__ bias, float* __restrict__ C,
            int M, int N, int K)
{
  __shared__ float As[8][132];
  __shared__ float Bs[8][132];
  const int tid = threadIdx.x;
  const int bm = blockIdx.y * 128;
  const int bn = blockIdx.x * 128;
  const int tx = tid & 15;
  const int ty = tid >> 4;
  float acc[2][2][4][4];
#pragma unroll
  for (int a = 0; a < 2; a++)
#pragma unroll
    for (int c = 0; c < 2; c++)
#pragma unroll
      for (int i = 0; i < 4; i++)
#pragma unroll
        for (int j = 0; j < 4; j++) acc[a][c][i][j] = 0.f;

  const int arow = tid >> 1;           // 0..127
  const int acol = (tid & 1) * 4;      // 0 or 4
  const int brow = tid >> 5;           // 0..7
  const int bcol = (tid & 31) * 4;     // 0..124
  const float* Ap = A + (size_t)(bm + arow) * K + acol;
  const float* Bp = W + (size_t)brow * N + bn + bcol;

  for (int k0 = 0; k0 < K; k0 += 8) {
    float4 av = *(const float4*)(Ap + k0);
    float4 bv = *(const float4*)(Bp + (size_t)k0 * N);
    As[acol + 0][arow] = av.x;
    As[acol + 1][arow] = av.y;
    As[acol + 2][arow] = av.z;
    As[acol + 3][arow] = av.w;
    *(float4*)&Bs[brow][bcol] = bv;
    __syncthreads();
#pragma unroll
    for (int k = 0; k < 8; ++k) {
      float4 a0 = *(const float4*)&As[k][ty * 4];
      float4 a1 = *(const float4*)&As[k][64 + ty * 4];
      float4 b0 = *(const float4*)&Bs[k][tx * 4];
      float4 b1 = *(const float4*)&Bs[k][64 + tx * 4];
      float ar[2][4] = {{a0.x, a0.y, a0.z, a0.w}, {a1.x, a1.y, a1.z, a1.w}};
      float br[2][4] = {{b0.x, b0.y, b0.z, b0.w}, {b1.x, b1.y, b1.z, b1.w}};
#pragma unroll
      for (int ri = 0; ri < 2; ri++)
#pragma unroll
        for (int i = 0; i < 4; i++)
#pragma unroll
          for (int ci = 0; ci < 2; ci++)
#pragma unroll
            for (int j = 0; j < 4; j++)
              acc[ri][ci][i][j] = fmaf(ar[ri][i], br[ci][j], acc[ri][ci][i][j]);
    }
    __syncthreads();
  }
#pragma unroll
  for (int ri = 0; ri < 2; ri++) {
#pragma unroll
    for (int i = 0; i < 4; i++) {
      const int row = bm + ri * 64 + ty * 4 + i;
#pragma unroll
      for (int ci = 0; ci < 2; ci++) {
        const int col = bn + ci * 64 + tx * 4;
        float4 bb = *(const float4*)&bias[col];
        float4 r;
        r.x = acc[ri][ci][i][0] + bb.x;
        r.y = acc[ri][ci][i][1] + bb.y;
        r.z = acc[ri][ci][i][2] + bb.z;
        r.w = acc[ri][ci][i][3] + bb.w;
        if (GELU) { r.x = gelu_f(r.x); r.y = gelu_f(r.y); r.z = gelu_f(r.z); r.w = gelu_f(r.w); }
        *(float4*)&C[(size_t)row * N + col] = r;
      }
    }
  }
}

// ---------------- fused flash attention -------------------------------------
// grid (B*H, S/64), 256 threads. Q/K/V layout [B,S,H,HD].
// mode 0: score += mask[b,k] (torch float key_padding_mask ADD semantics)
// mode 1: score += (mask>0 ? 0 : -1e9)
__global__ __launch_bounds__(256)
void attn_k(const float* __restrict__ Q, const float* __restrict__ Km,
            const float* __restrict__ Vm, const float* __restrict__ mask,
            float* __restrict__ O, int mode)
{
  __shared__ float qs[64][68];
  __shared__ float kps[64][68];   // K-tile, reused as P-tile
  __shared__ float vs[64][68];
  __shared__ float kb[64];
  const int tid = threadIdx.x;
  const int b = blockIdx.x >> 4;
  const int h = blockIdx.x & 15;
  const int q0 = blockIdx.y * 64;
  const int tx = tid & 15;
  const int ty = tid >> 4;
  const int lr = tid >> 2;
  const int lc = (tid & 3) * 16;

  {
    const float* qp = Q + ((size_t)(b * Ss + q0 + lr) * Dd) + h * HDd + lc;
#pragma unroll
    for (int ii = 0; ii < 16; ii += 4) {
      float4 t = *(const float4*)(qp + ii);
      t.x *= 0.125f; t.y *= 0.125f; t.z *= 0.125f; t.w *= 0.125f;  // 1/sqrt(64)
      *(float4*)&qs[lr][lc + ii] = t;
    }
  }
  float m_i[4], l_i[4], o_acc[4][4];
#pragma unroll
  for (int i = 0; i < 4; i++) {
    m_i[i] = -3.0e38f; l_i[i] = 0.f;
#pragma unroll
    for (int j = 0; j < 4; j++) o_acc[i][j] = 0.f;
  }

  for (int kt = 0; kt < Ss / 64; ++kt) {
    __syncthreads();                       // protect LDS from prev-iter reads
    const int k0 = kt * 64;
    {
      const float* kp = Km + ((size_t)(b * Ss + k0 + lr) * Dd) + h * HDd + lc;
      const float* vp = Vm + ((size_t)(b * Ss + k0 + lr) * Dd) + h * HDd + lc;
#pragma unroll
      for (int ii = 0; ii < 16; ii += 4) {
        *(float4*)&kps[lr][lc + ii] = *(const float4*)(kp + ii);
        *(float4*)&vs[lr][lc + ii]  = *(const float4*)(vp + ii);
      }
      if (tid < 64) {
        float mv = mask[b * Ss + k0 + tid];
        kb[tid] = mode ? (mv > 0.f ? 0.f : -1.0e9f) : mv;
      }
    }
    __syncthreads();
    float s[4][4];
#pragma unroll
    for (int i = 0; i < 4; i++)
#pragma unroll
      for (int j = 0; j < 4; j++) s[i][j] = 0.f;
    for (int d = 0; d < 64; d += 4) {
      float4 kv[4];
#pragma unroll
      for (int j = 0; j < 4; j++) kv[j] = *(const float4*)&kps[tx * 4 + j][d];
#pragma unroll
      for (int i = 0; i < 4; i++) {
        float4 qv = *(const float4*)&qs[ty * 4 + i][d];
#pragma unroll
        for (int j = 0; j < 4; j++)
          s[i][j] += qv.x * kv[j].x + qv.y * kv[j].y + qv.z * kv[j].z + qv.w * kv[j].w;
      }
    }
#pragma unroll
    for (int i = 0; i < 4; i++)
#pragma unroll
      for (int j = 0; j < 4; j++) s[i][j] += kb[tx * 4 + j];

    float p[4][4];
#pragma unroll
    for (int i = 0; i < 4; i++) {
      float mx = fmaxf(fmaxf(s[i][0], s[i][1]), fmaxf(s[i][2], s[i][3]));
#pragma unroll
      for (int off = 1; off < 16; off <<= 1) mx = fmaxf(mx, __shfl_xor(mx, off, 64));
      float mnew = fmaxf(m_i[i], mx);
      float sum = 0.f;
#pragma unroll
      for (int j = 0; j < 4; j++) { p[i][j] = expf(s[i][j] - mnew); sum += p[i][j]; }
#pragma unroll
      for (int off = 1; off < 16; off <<= 1) sum += __shfl_xor(sum, off, 64);
      float alpha = expf(m_i[i] - mnew);
      l_i[i] = l_i[i] * alpha + sum;
      m_i[i] = mnew;
#pragma unroll
      for (int j = 0; j < 4; j++) o_acc[i][j] *= alpha;
    }
    __syncthreads();                        // K-tile reads complete → reuse as P
#pragma unroll
    for (int i = 0; i < 4; i++)
      *(float4*)&kps[ty * 4 + i][tx * 4] = make_float4(p[i][0], p[i][1], p[i][2], p[i][3]);
    __syncthreads();
    for (int jj = 0; jj < 64; jj += 4) {
      float pr[4][4];
#pragma unroll
      for (int i = 0; i < 4; i++) {
        float4 pv4 = *(const float4*)&kps[ty * 4 + i][jj];
        pr[i][0] = pv4.x; pr[i][1] = pv4.y; pr[i][2] = pv4.z; pr[i][3] = pv4.w;
      }
#pragma unroll
      for (int kk = 0; kk < 4; ++kk) {
        float4 vv = *(const float4*)&vs[jj + kk][tx * 4];
#pragma unroll
        for (int i = 0; i < 4; i++) {
          o_acc[i][0] = fmaf(pr[i][kk], vv.x, o_acc[i][0]);
          o_acc[i][1] = fmaf(pr[i][kk], vv.y, o_acc[i][1]);
          o_acc[i][2] = fmaf(pr[i][kk], vv.z, o_acc[i][2]);
          o_acc[i][3] = fmaf(pr[i][kk], vv.w, o_acc[i][3]);
        }
      }
    }
  }
#pragma unroll
  for (int i = 0; i < 4; i++) {
    float inv = 1.0f / l_i[i];
    float4 r = make_float4(o_acc[i][0] * inv, o_acc[i][1] * inv,
                           o_acc[i][2] * inv, o_acc[i][3] * inv);
    *(float4*)&O[((size_t)(b * Ss + q0 + ty * 4 + i) * Dd) + h * HDd + tx * 4] = r;
  }
}

// ---------------- fused residual-add + LayerNorm ----------------------------
__global__ __launch_bounds__(256)
void ln_k(const float* __restrict__ X, const float* __restrict__ R,
          const float* __restrict__ g, const float* __restrict__ be,
          float* __restrict__ Out)
{
  __shared__ float red[8];
  const int row = blockIdx.x;
  const int tid = threadIdx.x;
  const int d = tid * 4;
  float4 xv = *(const float4*)(X + (size_t)row * Dd + d);
  float4 rv = *(const float4*)(R + (size_t)row * Dd + d);
  float v0 = xv.x + rv.x, v1 = xv.y + rv.y, v2 = xv.z + rv.z, v3 = xv.w + rv.w;
  float sum = v0 + v1 + v2 + v3;
#pragma unroll
  for (int off = 32; off; off >>= 1) sum += __shfl_xor(sum, off, 64);
  const int wave = tid >> 6, lane = tid & 63;
  if (lane == 0) red[wave] = sum;
  __syncthreads();
  float mean = (red[0] + red[1] + red[2] + red[3]) * (1.0f / Dd);
  float d0 = v0 - mean, d1 = v1 - mean, d2 = v2 - mean, d3 = v3 - mean;
  float ss = d0 * d0 + d1 * d1 + d2 * d2 + d3 * d3;
#pragma unroll
  for (int off = 32; off; off >>= 1) ss += __shfl_xor(ss, off, 64);
  if (lane == 0) red[4 + wave] = ss;
  __syncthreads();
  float var = (red[4] + red[5] + red[6] + red[7]) * (1.0f / Dd);
  float inv = 1.0f / sqrtf(var + 1e-5f);
  float4 gv = *(const float4*)(g + d);
  float4 bv = *(const float4*)(be + d);
  float4 r;
  r.x = d0 * inv * gv.x + bv.x;
  r.y = d1 * inv * gv.y + bv.y;
  r.z = d2 * inv * gv.z + bv.z;
  r.w = d3 * inv * gv.w + bv.w;
  *(float4*)&Out[(size_t)row * Dd + d] = r;
}

// ---------------- per-token sigmoid score: s = sigmoid(F @ Ws + bs) ---------
__global__ __launch_bounds__(256)
void score_k(const float* __restrict__ F, const float* __restrict__ Wsv,
             const float* __restrict__ bs, float* __restrict__ Sout)
{
  const int tok = blockIdx.x * 4 + (threadIdx.x >> 6);
  const int lane = threadIdx.x & 63;
  const float* fp = F + (size_t)tok * Dd;
  float acc = 0.f;
#pragma unroll
  for (int ii = 0; ii < 16; ++ii) {
    int d = lane + ii * 64;
    acc += fp[d] * Wsv[d];
  }
#pragma unroll
  for (int off = 32; off; off >>= 1) acc += __shfl_xor(acc, off, 64);
  if (lane == 0) Sout[tok] = 1.0f / (1.0f + expf(-(acc + bs[0])));
}

// ---------------- per-batch scan: sv, seg, new_mask -------------------------
__global__ __launch_bounds__(256)
void scan_k(const float* __restrict__ sin, const float* __restrict__ mask,
            float* __restrict__ svout, int* __restrict__ segout,
            float* __restrict__ nmask)
{
  __shared__ double sc[256];
  __shared__ float mxs[256];
  const int b = blockIdx.x;
  const int tid = threadIdx.x;
  const int t0 = tid * 4;
  float svl[4], mk[4];
  double loc[4];
  double run = 0.0;
#pragma unroll
  for (int i = 0; i < 4; i++) {
    float s = sin[b * Ss + t0 + i];
    float m = mask[b * Ss + t0 + i];
    float sv = (m > 0.f) ? s : 0.f;
    svl[i] = sv; mk[i] = m;
    run += (double)sv;
    loc[i] = run;
  }
  sc[tid] = run;
  __syncthreads();
  for (int off = 1; off < 256; off <<= 1) {
    double add = (tid >= off) ? sc[tid - off] : 0.0;
    __syncthreads();
    sc[tid] += add;
    __syncthreads();
  }
  double excl = sc[tid] - run;
  float lmax = -1.0f;
#pragma unroll
  for (int i = 0; i < 4; i++) {
    double c = floor(excl + loc[i]);
    int sg = (int)c;
    if (sg < 0) sg = 0;
    if (sg > Ss - 1) sg = Ss - 1;
    svout[b * Ss + t0 + i] = svl[i];
    segout[b * Ss + t0 + i] = sg;
    if (mk[i] > 0.f) lmax = fmaxf(lmax, (float)c);
  }
  mxs[tid] = lmax;
  __syncthreads();
  for (int off = 128; off; off >>= 1) {
    if (tid < off) mxs[tid] = fmaxf(mxs[tid], mxs[tid + off]);
    __syncthreads();
  }
  float mseg = mxs[0];
#pragma unroll
  for (int i = 0; i < 4; i++)
    nmask[b * Ss + t0 + i] = ((float)(t0 + i) <= mseg) ? 1.0f : 0.0f;
}

// ---------------- weighted segment scatter-add ------------------------------
__global__ __launch_bounds__(256)
void scatter_k(const float* __restrict__ X, const float* __restrict__ sv,
               const int* __restrict__ seg, float* __restrict__ pooled)
{
  const int tok = blockIdx.x;
  const float w = sv[tok];
  if (w == 0.f) return;
  const int b = tok >> 10;
  const int sg = seg[tok];
  const int d = threadIdx.x * 4;
  float4 xv = *(const float4*)(X + (size_t)tok * Dd + d);
  float* pp = pooled + ((size_t)(b * Ss + sg)) * Dd + d;
  atomicAdd(pp + 0, xv.x * w);
  atomicAdd(pp + 1, xv.y * w);
  atomicAdd(pp + 2, xv.z * w);
  atomicAdd(pp + 3, xv.w * w);
}

static inline void launch_gemm(const float* A, const float* W, const float* bias,
                               float* C, int M, int N, int K, bool gelu,
                               hipStream_t st)
{
  dim3 g(N / 128, M / 128), blk(256);
  if (gelu) hipLaunchKernelGGL((gemm_k<1>), g, blk, 0, st, A, W, bias, C, M, N, K);
  else      hipLaunchKernelGGL((gemm_k<0>), g, blk, 0, st, A, W, bias, C, M, N, K);
}

extern "C" void kernel_launch(void* const* d_in, const int* in_sizes, int n_in,
                              void* d_out, int out_size, void* d_ws, size_t ws_size,
                              hipStream_t stream)
{
  const float* x     = (const float*)d_in[0];
  const float* masks = (const float*)d_in[1];
  const float* Wq  = (const float*)d_in[2];
  const float* bq  = (const float*)d_in[3];
  const float* Wk  = (const float*)d_in[4];
  const float* bk  = (const float*)d_in[5];
  const float* Wv  = (const float*)d_in[6];
  const float* bv  = (const float*)d_in[7];
  const float* Wo  = (const float*)d_in[8];
  const float* bo  = (const float*)d_in[9];
  const float* g1  = (const float*)d_in[10];
  const float* be1 = (const float*)d_in[11];
  const float* g2  = (const float*)d_in[12];
  const float* be2 = (const float*)d_in[13];
  const float* W1  = (const float*)d_in[14];
  const float* bf1 = (const float*)d_in[15];
  const float* W2  = (const float*)d_in[16];
  const float* bf2 = (const float*)d_in[17];
  const float* Wsp = (const float*)d_in[18];
  const float* bs  = (const float*)d_in[19];
  const float* P1  = (const float*)d_in[20];
  const float* bp1 = (const float*)d_in[21];
  const float* P2  = (const float*)d_in[22];
  const float* bp2 = (const float*)d_in[23];

  float* ws = (float*)d_ws;
  const size_t ND = (size_t)NTOK * Dd;
  // Workspace plan (8*ND floats + smalls ≈ 134 MB), aliasing verified by
  // liveness order:
  //   q(0) k(1ND) v(2ND) ao(3ND) t1(4ND) h(5ND) ffh(6..8ND)
  //   feat/feat2 alias 6ND (written only after ffh dead; read before ffh write)
  //   pooled aliases t1 (t1 dead after enc2); hid aliases 0..4ND (q/k/v/ao dead)
  float* qb   = ws;
  float* kb_  = ws + ND;
  float* vb   = ws + 2 * ND;
  float* ao   = ws + 3 * ND;
  float* t1   = ws + 4 * ND;
  float* hb   = ws + 5 * ND;
  float* ffh  = ws + 6 * ND;       // 2*ND
  float* feat = ws + 6 * ND;       // alias of ffh (see ordering)
  float* sbuf = ws + 8 * ND;
  float* svb  = sbuf + NTOK;
  int*   segb = (int*)(sbuf + 2 * NTOK);
  float* pooled = t1;
  float* hid  = ws;                // 4*ND, over q/k/v/ao
  float* outp = (float*)d_out;
  float* nmask = outp + (size_t)NTOK * HIDh;

  auto enc = [&](const float* xin, float* fout, int mode) {
    launch_gemm(xin, Wq, bq, qb, NTOK, Dd, Dd, false, stream);
    launch_gemm(xin, Wk, bk, kb_, NTOK, Dd, Dd, false, stream);
    launch_gemm(xin, Wv, bv, vb, NTOK, Dd, Dd, false, stream);
    hipLaunchKernelGGL(attn_k, dim3(Bb * Hh, Ss / 64), dim3(256), 0, stream,
                       qb, kb_, vb, masks, ao, mode);
    launch_gemm(ao, Wo, bo, t1, NTOK, Dd, Dd, false, stream);
    hipLaunchKernelGGL(ln_k, dim3(NTOK), dim3(256), 0, stream, t1, xin, g1, be1, hb);
    // from here xin may be overwritten (ffh aliases feat)
    launch_gemm(hb, W1, bf1, ffh, NTOK, FFf, Dd, true, stream);
    launch_gemm(ffh, W2, bf2, t1, NTOK, Dd, FFf, false, stream);
    hipLaunchKernelGGL(ln_k, dim3(NTOK), dim3(256), 0, stream, t1, hb, g2, be2, fout);
  };

  enc(x, feat, 0);       // pass 1: float mask ADDED to scores
  enc(feat, feat, 1);    // pass 2: 0 / -1e9 mask

  hipLaunchKernelGGL(score_k, dim3(NTOK / 4), dim3(256), 0, stream, feat, Wsp, bs, sbuf);
  hipLaunchKernelGGL(scan_k, dim3(Bb), dim3(256), 0, stream, sbuf, masks, svb, segb, nmask);
  hipMemsetAsync(pooled, 0, ND * sizeof(float), stream);
  hipLaunchKernelGGL(scatter_k, dim3(NTOK), dim3(256), 0, stream, x, svb, segb, pooled);
  launch_gemm(pooled, P1, bp1, hid, NTOK, HIDh, Dd, true, stream);
  launch_gemm(hid, P2, bp2, outp, NTOK, HIDh, HIDh, false, stream);
}

// Round 3
// 4061.706 us; speedup vs baseline: 1.2846x; 1.2846x over previous
//
#include <hip/hip_runtime.h>

#define Bb 4
#define Ss 1024
#define Dd 1024
#define Hh 16
#define HDd 64
#define FFf 2048
#define HIDh 4096
#define NTOK (Bb*Ss)

typedef unsigned short ush;
typedef short v8s __attribute__((ext_vector_type(8)));
typedef float v4f __attribute__((ext_vector_type(4)));

__device__ __forceinline__ float gelu_f(float x) {
  return 0.5f * x * (1.0f + erff(x * 0.70710678118654752f));
}
__device__ __forceinline__ ush f2bf(float x) {
  unsigned int u = __float_as_uint(x);
  u += 0x7FFFu + ((u >> 16) & 1u);          // round-to-nearest-even
  return (ush)(u >> 16);
}
__device__ __forceinline__ float bf2f(ush h) {
  return __uint_as_float(((unsigned int)h) << 16);
}
__device__ __forceinline__ void gload16(const void* g, void* l) {
  __builtin_amdgcn_global_load_lds(
      (const __attribute__((address_space(1))) unsigned int*)g,
      (__attribute__((address_space(3))) unsigned int*)l, 16, 0, 0);
}

// ---------------- fp32 SGEMM (encoder path — bit-identical to R1) -----------
template<int GELU>
__global__ __launch_bounds__(256)
void gemm_k(const float* __restrict__ A, const float* __restrict__ W,
            const float* __restrict__ bias, float* __restrict__ C,
            int M, int N, int K)
{
  __shared__ float As[8][132];
  __shared__ float Bs[8][132];
  const int tid = threadIdx.x;
  const int bm = blockIdx.y * 128;
  const int bn = blockIdx.x * 128;
  const int tx = tid & 15;
  const int ty = tid >> 4;
  float acc[2][2][4][4];
#pragma unroll
  for (int a = 0; a < 2; a++)
#pragma unroll
    for (int c = 0; c < 2; c++)
#pragma unroll
      for (int i = 0; i < 4; i++)
#pragma unroll
        for (int j = 0; j < 4; j++) acc[a][c][i][j] = 0.f;

  const int arow = tid >> 1;
  const int acol = (tid & 1) * 4;
  const int brow = tid >> 5;
  const int bcol = (tid & 31) * 4;
  const float* Ap = A + (size_t)(bm + arow) * K + acol;
  const float* Bp = W + (size_t)brow * N + bn + bcol;

  for (int k0 = 0; k0 < K; k0 += 8) {
    float4 av = *(const float4*)(Ap + k0);
    float4 bv = *(const float4*)(Bp + (size_t)k0 * N);
    As[acol + 0][arow] = av.x;
    As[acol + 1][arow] = av.y;
    As[acol + 2][arow] = av.z;
    As[acol + 3][arow] = av.w;
    *(float4*)&Bs[brow][bcol] = bv;
    __syncthreads();
#pragma unroll
    for (int k = 0; k < 8; ++k) {
      float4 a0 = *(const float4*)&As[k][ty * 4];
      float4 a1 = *(const float4*)&As[k][64 + ty * 4];
      float4 b0 = *(const float4*)&Bs[k][tx * 4];
      float4 b1 = *(const float4*)&Bs[k][64 + tx * 4];
      float ar[2][4] = {{a0.x, a0.y, a0.z, a0.w}, {a1.x, a1.y, a1.z, a1.w}};
      float br[2][4] = {{b0.x, b0.y, b0.z, b0.w}, {b1.x, b1.y, b1.z, b1.w}};
#pragma unroll
      for (int ri = 0; ri < 2; ri++)
#pragma unroll
        for (int i = 0; i < 4; i++)
#pragma unroll
          for (int ci = 0; ci < 2; ci++)
#pragma unroll
            for (int j = 0; j < 4; j++)
              acc[ri][ci][i][j] = fmaf(ar[ri][i], br[ci][j], acc[ri][ci][i][j]);
    }
    __syncthreads();
  }
#pragma unroll
  for (int ri = 0; ri < 2; ri++) {
#pragma unroll
    for (int i = 0; i < 4; i++) {
      const int row = bm + ri * 64 + ty * 4 + i;
#pragma unroll
      for (int ci = 0; ci < 2; ci++) {
        const int col = bn + ci * 64 + tx * 4;
        float4 bb = *(const float4*)&bias[col];
        float4 r;
        r.x = acc[ri][ci][i][0] + bb.x;
        r.y = acc[ri][ci][i][1] + bb.y;
        r.z = acc[ri][ci][i][2] + bb.z;
        r.w = acc[ri][ci][i][3] + bb.w;
        if (GELU) { r.x = gelu_f(r.x); r.y = gelu_f(r.y); r.z = gelu_f(r.z); r.w = gelu_f(r.w); }
        *(float4*)&C[(size_t)row * N + col] = r;
      }
    }
  }
}

// ---------------- bf16x3 split GEMM (projector only — downstream of floor) --
template<int GELU>
__global__ __launch_bounds__(256)
void gemm3_k(const float* __restrict__ A, const ush* __restrict__ Bh,
             const ush* __restrict__ Bl, const float* __restrict__ bias,
             float* __restrict__ C, int M, int N, int K)
{
  __shared__ __align__(16) ush As0[128 * 32];
  __shared__ __align__(16) ush As1[128 * 32];
  __shared__ __align__(16) ush Bs0[128 * 32];
  __shared__ __align__(16) ush Bs1[128 * 32];
  const int tid = threadIdx.x;
  const int lane = tid & 63, wave = tid >> 6;
  const int bm = blockIdx.y * 128, bn = blockIdx.x * 128;
  const int wm = (wave & 1) * 64, wn = (wave >> 1) * 64;

  v4f acc[4][4] = {};

  const int ma = tid >> 3;
  const int ka = (tid & 7) * 4;
  const float* Ap = A + (size_t)(bm + ma) * K + ka;

  const int nb = bn + wave * 32 + (lane >> 2);
  const int kb = (lane & 3) * 8;
  const ush* g0h = Bh + (size_t)nb * K + kb;
  const ush* g1h = g0h + (size_t)16 * K;
  const ush* g0l = Bl + (size_t)nb * K + kb;
  const ush* g1l = g0l + (size_t)16 * K;
  ush* lb0h = &Bs0[wave * 1024];
  ush* lb1h = &Bs0[wave * 1024 + 512];
  ush* lb0l = &Bs1[wave * 1024];
  ush* lb1l = &Bs1[wave * 1024 + 512];

  const int fr = lane & 15;
  const int fq = (lane >> 4) * 8;

  for (int k0 = 0; k0 < K; k0 += 32) {
    gload16(g0h + k0, lb0h);
    gload16(g1h + k0, lb1h);
    gload16(g0l + k0, lb0l);
    gload16(g1l + k0, lb1l);
#pragma unroll
    for (int p = 0; p < 4; ++p) {
      float4 v = *(const float4*)(Ap + (size_t)p * 32 * K + k0);
      ushort4 h, l;
      h.x = f2bf(v.x); l.x = f2bf(v.x - bf2f(h.x));
      h.y = f2bf(v.y); l.y = f2bf(v.y - bf2f(h.y));
      h.z = f2bf(v.z); l.z = f2bf(v.z - bf2f(h.z));
      h.w = f2bf(v.w); l.w = f2bf(v.w - bf2f(h.w));
      const int off = (ma + p * 32) * 32 + ka;
      *(ushort4*)&As0[off] = h;
      *(ushort4*)&As1[off] = l;
    }
    __syncthreads();
    v8s afh[4], afl[4];
#pragma unroll
    for (int mi = 0; mi < 4; ++mi) {
      const int o = (wm + mi * 16 + fr) * 32 + fq;
      afh[mi] = *(const v8s*)&As0[o];
      afl[mi] = *(const v8s*)&As1[o];
    }
#pragma unroll
    for (int ni = 0; ni < 4; ++ni) {
      const int o = (wn + ni * 16 + fr) * 32 + fq;
      v8s bh = *(const v8s*)&Bs0[o];
      v8s bl = *(const v8s*)&Bs1[o];
#pragma unroll
      for (int mi = 0; mi < 4; ++mi) {
        acc[mi][ni] = __builtin_amdgcn_mfma_f32_16x16x32_bf16(afh[mi], bh, acc[mi][ni], 0, 0, 0);
        acc[mi][ni] = __builtin_amdgcn_mfma_f32_16x16x32_bf16(afh[mi], bl, acc[mi][ni], 0, 0, 0);
        acc[mi][ni] = __builtin_amdgcn_mfma_f32_16x16x32_bf16(afl[mi], bh, acc[mi][ni], 0, 0, 0);
      }
    }
    __syncthreads();
  }
  const int eq = (lane >> 4) * 4;
#pragma unroll
  for (int ni = 0; ni < 4; ++ni) {
    const int col = bn + wn + ni * 16 + fr;
    const float bv = bias[col];
#pragma unroll
    for (int mi = 0; mi < 4; ++mi) {
      const int row0 = bm + wm + mi * 16 + eq;
#pragma unroll
      for (int r = 0; r < 4; ++r) {
        float v = acc[mi][ni][r] + bv;
        if (GELU) v = gelu_f(v);
        C[(size_t)(row0 + r) * N + col] = v;
      }
    }
  }
}

// ---------------- weight transpose + bf16 hi/lo split -----------------------
__global__ __launch_bounds__(256)
void wt_k(const float* __restrict__ W, ush* __restrict__ Th, ush* __restrict__ Tl,
          int K, int N)
{
  __shared__ float tile[32][33];
  const int k0 = blockIdx.y * 32, n0 = blockIdx.x * 32;
  const int tx = threadIdx.x & 31, ty = threadIdx.x >> 5;
#pragma unroll
  for (int j = 0; j < 32; j += 8)
    tile[ty + j][tx] = W[(size_t)(k0 + ty + j) * N + n0 + tx];
  __syncthreads();
#pragma unroll
  for (int j = 0; j < 32; j += 8) {
    float v = tile[tx][ty + j];
    ush h = f2bf(v);
    ush l = f2bf(v - bf2f(h));
    size_t o = (size_t)(n0 + ty + j) * K + k0 + tx;
    Th[o] = h;
    Tl[o] = l;
  }
}

// ---------------- fused flash attention (R1, fp32) --------------------------
__global__ __launch_bounds__(256)
void attn_k(const float* __restrict__ Q, const float* __restrict__ Km,
            const float* __restrict__ Vm, const float* __restrict__ mask,
            float* __restrict__ O, int mode)
{
  __shared__ float qs[64][68];
  __shared__ float kps[64][68];
  __shared__ float vs[64][68];
  __shared__ float kb[64];
  const int tid = threadIdx.x;
  const int b = blockIdx.x >> 4;
  const int h = blockIdx.x & 15;
  const int q0 = blockIdx.y * 64;
  const int tx = tid & 15;
  const int ty = tid >> 4;
  const int lr = tid >> 2;
  const int lc = (tid & 3) * 16;

  {
    const float* qp = Q + ((size_t)(b * Ss + q0 + lr) * Dd) + h * HDd + lc;
#pragma unroll
    for (int ii = 0; ii < 16; ii += 4) {
      float4 t = *(const float4*)(qp + ii);
      t.x *= 0.125f; t.y *= 0.125f; t.z *= 0.125f; t.w *= 0.125f;
      *(float4*)&qs[lr][lc + ii] = t;
    }
  }
  float m_i[4], l_i[4], o_acc[4][4];
#pragma unroll
  for (int i = 0; i < 4; i++) {
    m_i[i] = -3.0e38f; l_i[i] = 0.f;
#pragma unroll
    for (int j = 0; j < 4; j++) o_acc[i][j] = 0.f;
  }

  for (int kt = 0; kt < Ss / 64; ++kt) {
    __syncthreads();
    const int k0 = kt * 64;
    {
      const float* kp = Km + ((size_t)(b * Ss + k0 + lr) * Dd) + h * HDd + lc;
      const float* vp = Vm + ((size_t)(b * Ss + k0 + lr) * Dd) + h * HDd + lc;
#pragma unroll
      for (int ii = 0; ii < 16; ii += 4) {
        *(float4*)&kps[lr][lc + ii] = *(const float4*)(kp + ii);
        *(float4*)&vs[lr][lc + ii]  = *(const float4*)(vp + ii);
      }
      if (tid < 64) {
        float mv = mask[b * Ss + k0 + tid];
        kb[tid] = mode ? (mv > 0.f ? 0.f : -1.0e9f) : mv;
      }
    }
    __syncthreads();
    float s[4][4];
#pragma unroll
    for (int i = 0; i < 4; i++)
#pragma unroll
      for (int j = 0; j < 4; j++) s[i][j] = 0.f;
    for (int d = 0; d < 64; d += 4) {
      float4 kv[4];
#pragma unroll
      for (int j = 0; j < 4; j++) kv[j] = *(const float4*)&kps[tx * 4 + j][d];
#pragma unroll
      for (int i = 0; i < 4; i++) {
        float4 qv = *(const float4*)&qs[ty * 4 + i][d];
#pragma unroll
        for (int j = 0; j < 4; j++)
          s[i][j] += qv.x * kv[j].x + qv.y * kv[j].y + qv.z * kv[j].z + qv.w * kv[j].w;
      }
    }
#pragma unroll
    for (int i = 0; i < 4; i++)
#pragma unroll
      for (int j = 0; j < 4; j++) s[i][j] += kb[tx * 4 + j];

    float p[4][4];
#pragma unroll
    for (int i = 0; i < 4; i++) {
      float mx = fmaxf(fmaxf(s[i][0], s[i][1]), fmaxf(s[i][2], s[i][3]));
#pragma unroll
      for (int off = 1; off < 16; off <<= 1) mx = fmaxf(mx, __shfl_xor(mx, off, 64));
      float mnew = fmaxf(m_i[i], mx);
      float sum = 0.f;
#pragma unroll
      for (int j = 0; j < 4; j++) { p[i][j] = expf(s[i][j] - mnew); sum += p[i][j]; }
#pragma unroll
      for (int off = 1; off < 16; off <<= 1) sum += __shfl_xor(sum, off, 64);
      float alpha = expf(m_i[i] - mnew);
      l_i[i] = l_i[i] * alpha + sum;
      m_i[i] = mnew;
#pragma unroll
      for (int j = 0; j < 4; j++) o_acc[i][j] *= alpha;
    }
    __syncthreads();
#pragma unroll
    for (int i = 0; i < 4; i++)
      *(float4*)&kps[ty * 4 + i][tx * 4] = make_float4(p[i][0], p[i][1], p[i][2], p[i][3]);
    __syncthreads();
    for (int jj = 0; jj < 64; jj += 4) {
      float pr[4][4];
#pragma unroll
      for (int i = 0; i < 4; i++) {
        float4 pv4 = *(const float4*)&kps[ty * 4 + i][jj];
        pr[i][0] = pv4.x; pr[i][1] = pv4.y; pr[i][2] = pv4.z; pr[i][3] = pv4.w;
      }
#pragma unroll
      for (int kk = 0; kk < 4; ++kk) {
        float4 vv = *(const float4*)&vs[jj + kk][tx * 4];
#pragma unroll
        for (int i = 0; i < 4; i++) {
          o_acc[i][0] = fmaf(pr[i][kk], vv.x, o_acc[i][0]);
          o_acc[i][1] = fmaf(pr[i][kk], vv.y, o_acc[i][1]);
          o_acc[i][2] = fmaf(pr[i][kk], vv.z, o_acc[i][2]);
          o_acc[i][3] = fmaf(pr[i][kk], vv.w, o_acc[i][3]);
        }
      }
    }
  }
#pragma unroll
  for (int i = 0; i < 4; i++) {
    float inv = 1.0f / l_i[i];
    float4 r = make_float4(o_acc[i][0] * inv, o_acc[i][1] * inv,
                           o_acc[i][2] * inv, o_acc[i][3] * inv);
    *(float4*)&O[((size_t)(b * Ss + q0 + ty * 4 + i) * Dd) + h * HDd + tx * 4] = r;
  }
}

// ---------------- fused residual-add + LayerNorm ----------------------------
__global__ __launch_bounds__(256)
void ln_k(const float* __restrict__ X, const float* __restrict__ R,
          const float* __restrict__ g, const float* __restrict__ be,
          float* __restrict__ Out)
{
  __shared__ float red[8];
  const int row = blockIdx.x;
  const int tid = threadIdx.x;
  const int d = tid * 4;
  float4 xv = *(const float4*)(X + (size_t)row * Dd + d);
  float4 rv = *(const float4*)(R + (size_t)row * Dd + d);
  float v0 = xv.x + rv.x, v1 = xv.y + rv.y, v2 = xv.z + rv.z, v3 = xv.w + rv.w;
  float sum = v0 + v1 + v2 + v3;
#pragma unroll
  for (int off = 32; off; off >>= 1) sum += __shfl_xor(sum, off, 64);
  const int wave = tid >> 6, lane = tid & 63;
  if (lane == 0) red[wave] = sum;
  __syncthreads();
  float mean = (red[0] + red[1] + red[2] + red[3]) * (1.0f / Dd);
  float d0 = v0 - mean, d1 = v1 - mean, d2 = v2 - mean, d3 = v3 - mean;
  float ss = d0 * d0 + d1 * d1 + d2 * d2 + d3 * d3;
#pragma unroll
  for (int off = 32; off; off >>= 1) ss += __shfl_xor(ss, off, 64);
  if (lane == 0) red[4 + wave] = ss;
  __syncthreads();
  float var = (red[4] + red[5] + red[6] + red[7]) * (1.0f / Dd);
  float inv = 1.0f / sqrtf(var + 1e-5f);
  float4 gv = *(const float4*)(g + d);
  float4 bv = *(const float4*)(be + d);
  float4 r;
  r.x = d0 * inv * gv.x + bv.x;
  r.y = d1 * inv * gv.y + bv.y;
  r.z = d2 * inv * gv.z + bv.z;
  r.w = d3 * inv * gv.w + bv.w;
  *(float4*)&Out[(size_t)row * Dd + d] = r;
}

// ---------------- per-token sigmoid score -----------------------------------
__global__ __launch_bounds__(256)
void score_k(const float* __restrict__ F, const float* __restrict__ Wsv,
             const float* __restrict__ bs, float* __restrict__ Sout)
{
  const int tok = blockIdx.x * 4 + (threadIdx.x >> 6);
  const int lane = threadIdx.x & 63;
  const float* fp = F + (size_t)tok * Dd;
  float acc = 0.f;
#pragma unroll
  for (int ii = 0; ii < 16; ++ii) {
    int d = lane + ii * 64;
    acc += fp[d] * Wsv[d];
  }
#pragma unroll
  for (int off = 32; off; off >>= 1) acc += __shfl_xor(acc, off, 64);
  if (lane == 0) Sout[tok] = 1.0f / (1.0f + expf(-(acc + bs[0])));
}

// ---------------- per-batch scan: sv, seg, new_mask -------------------------
__global__ __launch_bounds__(256)
void scan_k(const float* __restrict__ sin, const float* __restrict__ mask,
            float* __restrict__ svout, int* __restrict__ segout,
            float* __restrict__ nmask)
{
  __shared__ double sc[256];
  __shared__ float mxs[256];
  const int b = blockIdx.x;
  const int tid = threadIdx.x;
  const int t0 = tid * 4;
  float svl[4], mk[4];
  double loc[4];
  double run = 0.0;
#pragma unroll
  for (int i = 0; i < 4; i++) {
    float s = sin[b * Ss + t0 + i];
    float m = mask[b * Ss + t0 + i];
    float sv = (m > 0.f) ? s : 0.f;
    svl[i] = sv; mk[i] = m;
    run += (double)sv;
    loc[i] = run;
  }
  sc[tid] = run;
  __syncthreads();
  for (int off = 1; off < 256; off <<= 1) {
    double add = (tid >= off) ? sc[tid - off] : 0.0;
    __syncthreads();
    sc[tid] += add;
    __syncthreads();
  }
  double excl = sc[tid] - run;
  float lmax = -1.0f;
#pragma unroll
  for (int i = 0; i < 4; i++) {
    double c = floor(excl + loc[i]);
    int sg = (int)c;
    if (sg < 0) sg = 0;
    if (sg > Ss - 1) sg = Ss - 1;
    svout[b * Ss + t0 + i] = svl[i];
    segout[b * Ss + t0 + i] = sg;
    if (mk[i] > 0.f) lmax = fmaxf(lmax, (float)c);
  }
  mxs[tid] = lmax;
  __syncthreads();
  for (int off = 128; off; off >>= 1) {
    if (tid < off) mxs[tid] = fmaxf(mxs[tid], mxs[tid + off]);
    __syncthreads();
  }
  float mseg = mxs[0];
#pragma unroll
  for (int i = 0; i < 4; i++)
    nmask[b * Ss + t0 + i] = ((float)(t0 + i) <= mseg) ? 1.0f : 0.0f;
}

// ---------------- weighted segment scatter-add ------------------------------
__global__ __launch_bounds__(256)
void scatter_k(const float* __restrict__ X, const float* __restrict__ sv,
               const int* __restrict__ seg, float* __restrict__ pooled)
{
  const int tok = blockIdx.x;
  const float w = sv[tok];
  if (w == 0.f) return;
  const int b = tok >> 10;
  const int sg = seg[tok];
  const int d = threadIdx.x * 4;
  float4 xv = *(const float4*)(X + (size_t)tok * Dd + d);
  float* pp = pooled + ((size_t)(b * Ss + sg)) * Dd + d;
  atomicAdd(pp + 0, xv.x * w);
  atomicAdd(pp + 1, xv.y * w);
  atomicAdd(pp + 2, xv.z * w);
  atomicAdd(pp + 3, xv.w * w);
}

static inline void launch_gemm(const float* A, const float* W, const float* bias,
                               float* C, int M, int N, int K, bool gelu,
                               hipStream_t st)
{
  dim3 g(N / 128, M / 128), blk(256);
  if (gelu) hipLaunchKernelGGL((gemm_k<1>), g, blk, 0, st, A, W, bias, C, M, N, K);
  else      hipLaunchKernelGGL((gemm_k<0>), g, blk, 0, st, A, W, bias, C, M, N, K);
}

static inline void launch_gemm3(const float* A, const ush* Bh, const ush* Bl,
                                const float* bias, float* C, int M, int N, int K,
                                bool gelu, hipStream_t st)
{
  dim3 g(N / 128, M / 128), blk(256);
  if (gelu) hipLaunchKernelGGL((gemm3_k<1>), g, blk, 0, st, A, Bh, Bl, bias, C, M, N, K);
  else      hipLaunchKernelGGL((gemm3_k<0>), g, blk, 0, st, A, Bh, Bl, bias, C, M, N, K);
}

extern "C" void kernel_launch(void* const* d_in, const int* in_sizes, int n_in,
                              void* d_out, int out_size, void* d_ws, size_t ws_size,
                              hipStream_t stream)
{
  const float* x     = (const float*)d_in[0];
  const float* masks = (const float*)d_in[1];
  const float* Wq  = (const float*)d_in[2];
  const float* bq  = (const float*)d_in[3];
  const float* Wk  = (const float*)d_in[4];
  const float* bk  = (const float*)d_in[5];
  const float* Wv  = (const float*)d_in[6];
  const float* bv  = (const float*)d_in[7];
  const float* Wo  = (const float*)d_in[8];
  const float* bo  = (const float*)d_in[9];
  const float* g1  = (const float*)d_in[10];
  const float* be1 = (const float*)d_in[11];
  const float* g2  = (const float*)d_in[12];
  const float* be2 = (const float*)d_in[13];
  const float* W1  = (const float*)d_in[14];
  const float* bf1 = (const float*)d_in[15];
  const float* W2  = (const float*)d_in[16];
  const float* bf2 = (const float*)d_in[17];
  const float* Wsp = (const float*)d_in[18];
  const float* bs  = (const float*)d_in[19];
  const float* P1  = (const float*)d_in[20];
  const float* bp1 = (const float*)d_in[21];
  const float* P2  = (const float*)d_in[22];
  const float* bp2 = (const float*)d_in[23];

  // ---- workspace: R1's exact 8*ND + smalls footprint (134.3 MB) ----------
  // Encoder phase (identical to R1): u0 qb / u1 kb / u2 vb / u3 ao / u4 t1 /
  //   u5 hb / u6..u7 ffh (feat aliases u6).
  // Projector phase liveness:
  //   pooled = u4 (t1 dead after enc2)
  //   P1t    = u7 region, 8M ush = 16 MB (ffh dead; feat=u6 untouched)
  //   hid    = u0..u3 (4*ND fp32 = 67.1 MB; qb/kb/vb/ao dead)
  //   P2t    = u4..u7 region, 32M ush = 64 MB (pooled/P1t/feat dead after P1)
  const size_t ND = (size_t)NTOK * Dd;      // 4.19M floats
  float* fb = (float*)d_ws;
  float* u0 = fb + 0 * ND;
  float* u2 = fb + 2 * ND;
  float* u3 = fb + 3 * ND;
  float* u4 = fb + 4 * ND;
  float* u5 = fb + 5 * ND;
  float* u6 = fb + 6 * ND;
  float* u7 = fb + 7 * ND;
  float* sbuf = fb + 8 * ND;
  float* svb  = sbuf + NTOK;
  int*   segb = (int*)(sbuf + 2 * NTOK);

  float* qb = u0, *kb_ = fb + ND, *vb = u2, *ao = u3, *t1 = u4, *hb = u5, *feat = u6;
  float* ffh = u6;                   // NTOK x FF spans u6+u7
  float* pooled = u4;
  float* hid = u0;                   // NTOK x HID spans u0..u3
  ush*   p1h = (ush*)u7;             // 16 MB in u7
  ush*   p1l = p1h + (size_t)Dd * HIDh;
  ush*   p2h = (ush*)u4;             // 64 MB spans u4..u7
  ush*   p2l = p2h + (size_t)HIDh * HIDh;
  float* outp = (float*)d_out;
  float* nmask = outp + (size_t)NTOK * HIDh;

  auto enc = [&](const float* xin, float* fout, int mode) {
    launch_gemm(xin, Wq, bq, qb, NTOK, Dd, Dd, false, stream);
    launch_gemm(xin, Wk, bk, kb_, NTOK, Dd, Dd, false, stream);
    launch_gemm(xin, Wv, bv, vb, NTOK, Dd, Dd, false, stream);
    hipLaunchKernelGGL(attn_k, dim3(Bb * Hh, Ss / 64), dim3(256), 0, stream,
                       qb, kb_, vb, masks, ao, mode);
    launch_gemm(ao, Wo, bo, t1, NTOK, Dd, Dd, false, stream);
    hipLaunchKernelGGL(ln_k, dim3(NTOK), dim3(256), 0, stream, t1, xin, g1, be1, hb);
    // xin (u6 in pass 2) dead from here; ffh overwrites u6/u7
    launch_gemm(hb, W1, bf1, ffh, NTOK, FFf, Dd, true, stream);
    launch_gemm(ffh, W2, bf2, t1, NTOK, Dd, FFf, false, stream);
    hipLaunchKernelGGL(ln_k, dim3(NTOK), dim3(256), 0, stream, t1, hb, g2, be2, fout);
  };

  enc(x, feat, 0);       // pass 1: float mask ADDED to scores
  enc(feat, feat, 1);    // pass 2: 0 / -1e9 mask

  hipLaunchKernelGGL(score_k, dim3(NTOK / 4), dim3(256), 0, stream, feat, Wsp, bs, sbuf);
  hipLaunchKernelGGL(scan_k, dim3(Bb), dim3(256), 0, stream, sbuf, masks, svb, segb, nmask);
  hipMemsetAsync(pooled, 0, ND * sizeof(float), stream);
  hipLaunchKernelGGL(scatter_k, dim3(NTOK), dim3(256), 0, stream, x, svb, segb, pooled);

  // projector (bf16x3 MFMA — downstream of the floor, smooth error only)
  hipLaunchKernelGGL(wt_k, dim3(HIDh / 32, Dd / 32), dim3(256), 0, stream, P1, p1h, p1l, Dd, HIDh);
  launch_gemm3(pooled, p1h, p1l, bp1, hid, NTOK, HIDh, Dd, true, stream);
  hipLaunchKernelGGL(wt_k, dim3(HIDh / 32, HIDh / 32), dim3(256), 0, stream, P2, p2h, p2l, HIDh, HIDh);
  launch_gemm3(hid, p2h, p2l, bp2, outp, NTOK, HIDh, HIDh, false, stream);
}

// Round 4
// 2565.236 us; speedup vs baseline: 2.0340x; 1.5834x over previous
//
#include <hip/hip_runtime.h>

#define Bb 4
#define Ss 1024
#define Dd 1024
#define Hh 16
#define HDd 64
#define FFf 2048
#define HIDh 4096
#define NTOK (Bb*Ss)

typedef unsigned short ush;
typedef short v8s __attribute__((ext_vector_type(8)));
typedef float v4f __attribute__((ext_vector_type(4)));

__device__ __forceinline__ float gelu_f(float x) {
  return 0.5f * x * (1.0f + erff(x * 0.70710678118654752f));
}
__device__ __forceinline__ ush f2bf(float x) {              // RNE
  unsigned int u = __float_as_uint(x);
  u += 0x7FFFu + ((u >> 16) & 1u);
  return (ush)(u >> 16);
}
__device__ __forceinline__ ush f2bf_t(float x) {            // truncate
  return (ush)(__float_as_uint(x) >> 16);
}
__device__ __forceinline__ float bf2f(ush h) {
  return __uint_as_float(((unsigned int)h) << 16);
}
__device__ __forceinline__ void gload16(const void* g, void* l) {
  __builtin_amdgcn_global_load_lds(
      (const __attribute__((address_space(1))) unsigned int*)g,
      (__attribute__((address_space(3))) unsigned int*)l, 16, 0, 0);
}

// ---------------- bf16x6 split GEMM (fp32-fidelity, encoder path) -----------
// C = A(fp32)[M,K] @ W[K,N] + bias. W pre-split 3-plane bf16 [N][K] (h RNE,
// m/l trunc). A split 3-plane in-kernel. 6 MFMAs: hh,hm,mh,hl,lh,mm →
// dropped terms ~2^-24 rel — safe upstream of the floor() segmentation.
template<int GELU>
__global__ __launch_bounds__(256)
void gemm6_k(const float* __restrict__ A, const ush* __restrict__ Bh,
             const ush* __restrict__ Bm, const ush* __restrict__ Bl,
             const float* __restrict__ bias, float* __restrict__ C,
             int M, int N, int K)
{
  __shared__ __align__(16) ush As0[128 * 32];
  __shared__ __align__(16) ush As1[128 * 32];
  __shared__ __align__(16) ush As2[128 * 32];
  __shared__ __align__(16) ush Bs0[128 * 32];
  __shared__ __align__(16) ush Bs1[128 * 32];
  __shared__ __align__(16) ush Bs2[128 * 32];
  const int tid = threadIdx.x;
  const int lane = tid & 63, wave = tid >> 6;
  const int bm = blockIdx.y * 128, bn = blockIdx.x * 128;
  const int wm = (wave & 1) * 64, wn = (wave >> 1) * 64;

  v4f acc[4][4] = {};

  const int ma = tid >> 3;             // 0..31
  const int ka = (tid & 7) * 4;        // 0..28
  const float* Ap = A + (size_t)(bm + ma) * K + ka;

  const int nb = bn + wave * 32 + (lane >> 2);
  const int kb = (lane & 3) * 8;
  const ush* gh0 = Bh + (size_t)nb * K + kb;
  const ush* gm0 = Bm + (size_t)nb * K + kb;
  const ush* gl0 = Bl + (size_t)nb * K + kb;
  const size_t row16 = (size_t)16 * K;
  ush* lbh0 = &Bs0[wave * 1024]; ush* lbh1 = lbh0 + 512;
  ush* lbm0 = &Bs1[wave * 1024]; ush* lbm1 = lbm0 + 512;
  ush* lbl0 = &Bs2[wave * 1024]; ush* lbl1 = lbl0 + 512;

  const int fr = lane & 15;
  const int fq = (lane >> 4) * 8;

  for (int k0 = 0; k0 < K; k0 += 32) {
    gload16(gh0 + k0, lbh0);
    gload16(gh0 + row16 + k0, lbh1);
    gload16(gm0 + k0, lbm0);
    gload16(gm0 + row16 + k0, lbm1);
    gload16(gl0 + k0, lbl0);
    gload16(gl0 + row16 + k0, lbl1);
#pragma unroll
    for (int p = 0; p < 4; ++p) {
      float4 v = *(const float4*)(Ap + (size_t)p * 32 * K + k0);
      ushort4 h, m, l;
      float r;
      h.x = f2bf(v.x); r = v.x - bf2f(h.x); m.x = f2bf_t(r); l.x = f2bf_t(r - bf2f(m.x));
      h.y = f2bf(v.y); r = v.y - bf2f(h.y); m.y = f2bf_t(r); l.y = f2bf_t(r - bf2f(m.y));
      h.z = f2bf(v.z); r = v.z - bf2f(h.z); m.z = f2bf_t(r); l.z = f2bf_t(r - bf2f(m.z));
      h.w = f2bf(v.w); r = v.w - bf2f(h.w); m.w = f2bf_t(r); l.w = f2bf_t(r - bf2f(m.w));
      const int off = (ma + p * 32) * 32 + ka;
      *(ushort4*)&As0[off] = h;
      *(ushort4*)&As1[off] = m;
      *(ushort4*)&As2[off] = l;
    }
    __syncthreads();
    v8s ah[4], am[4], al[4];
#pragma unroll
    for (int mi = 0; mi < 4; ++mi) {
      const int o = (wm + mi * 16 + fr) * 32 + fq;
      ah[mi] = *(const v8s*)&As0[o];
      am[mi] = *(const v8s*)&As1[o];
      al[mi] = *(const v8s*)&As2[o];
    }
#pragma unroll
    for (int ni = 0; ni < 4; ++ni) {
      const int o = (wn + ni * 16 + fr) * 32 + fq;
      v8s bh = *(const v8s*)&Bs0[o];
      v8s bm_ = *(const v8s*)&Bs1[o];
      v8s bl = *(const v8s*)&Bs2[o];
#pragma unroll
      for (int mi = 0; mi < 4; ++mi) {
        acc[mi][ni] = __builtin_amdgcn_mfma_f32_16x16x32_bf16(ah[mi], bh,  acc[mi][ni], 0, 0, 0);
        acc[mi][ni] = __builtin_amdgcn_mfma_f32_16x16x32_bf16(ah[mi], bm_, acc[mi][ni], 0, 0, 0);
        acc[mi][ni] = __builtin_amdgcn_mfma_f32_16x16x32_bf16(am[mi], bh,  acc[mi][ni], 0, 0, 0);
        acc[mi][ni] = __builtin_amdgcn_mfma_f32_16x16x32_bf16(ah[mi], bl,  acc[mi][ni], 0, 0, 0);
        acc[mi][ni] = __builtin_amdgcn_mfma_f32_16x16x32_bf16(al[mi], bh,  acc[mi][ni], 0, 0, 0);
        acc[mi][ni] = __builtin_amdgcn_mfma_f32_16x16x32_bf16(am[mi], bm_, acc[mi][ni], 0, 0, 0);
      }
    }
    __syncthreads();
  }
  const int eq = (lane >> 4) * 4;
#pragma unroll
  for (int ni = 0; ni < 4; ++ni) {
    const int col = bn + wn + ni * 16 + fr;
    const float bv = bias[col];
#pragma unroll
    for (int mi = 0; mi < 4; ++mi) {
      const int row0 = bm + wm + mi * 16 + eq;
#pragma unroll
      for (int r = 0; r < 4; ++r) {
        float v = acc[mi][ni][r] + bv;
        if (GELU) v = gelu_f(v);
        C[(size_t)(row0 + r) * N + col] = v;
      }
    }
  }
}

// ---------------- bf16x3 split GEMM (projector — downstream of floor) -------
template<int GELU>
__global__ __launch_bounds__(256)
void gemm3_k(const float* __restrict__ A, const ush* __restrict__ Bh,
             const ush* __restrict__ Bl, const float* __restrict__ bias,
             float* __restrict__ C, int M, int N, int K)
{
  __shared__ __align__(16) ush As0[128 * 32];
  __shared__ __align__(16) ush As1[128 * 32];
  __shared__ __align__(16) ush Bs0[128 * 32];
  __shared__ __align__(16) ush Bs1[128 * 32];
  const int tid = threadIdx.x;
  const int lane = tid & 63, wave = tid >> 6;
  const int bm = blockIdx.y * 128, bn = blockIdx.x * 128;
  const int wm = (wave & 1) * 64, wn = (wave >> 1) * 64;

  v4f acc[4][4] = {};

  const int ma = tid >> 3;
  const int ka = (tid & 7) * 4;
  const float* Ap = A + (size_t)(bm + ma) * K + ka;

  const int nb = bn + wave * 32 + (lane >> 2);
  const int kb = (lane & 3) * 8;
  const ush* g0h = Bh + (size_t)nb * K + kb;
  const ush* g1h = g0h + (size_t)16 * K;
  const ush* g0l = Bl + (size_t)nb * K + kb;
  const ush* g1l = g0l + (size_t)16 * K;
  ush* lb0h = &Bs0[wave * 1024];
  ush* lb1h = &Bs0[wave * 1024 + 512];
  ush* lb0l = &Bs1[wave * 1024];
  ush* lb1l = &Bs1[wave * 1024 + 512];

  const int fr = lane & 15;
  const int fq = (lane >> 4) * 8;

  for (int k0 = 0; k0 < K; k0 += 32) {
    gload16(g0h + k0, lb0h);
    gload16(g1h + k0, lb1h);
    gload16(g0l + k0, lb0l);
    gload16(g1l + k0, lb1l);
#pragma unroll
    for (int p = 0; p < 4; ++p) {
      float4 v = *(const float4*)(Ap + (size_t)p * 32 * K + k0);
      ushort4 h, l;
      h.x = f2bf(v.x); l.x = f2bf(v.x - bf2f(h.x));
      h.y = f2bf(v.y); l.y = f2bf(v.y - bf2f(h.y));
      h.z = f2bf(v.z); l.z = f2bf(v.z - bf2f(h.z));
      h.w = f2bf(v.w); l.w = f2bf(v.w - bf2f(h.w));
      const int off = (ma + p * 32) * 32 + ka;
      *(ushort4*)&As0[off] = h;
      *(ushort4*)&As1[off] = l;
    }
    __syncthreads();
    v8s afh[4], afl[4];
#pragma unroll
    for (int mi = 0; mi < 4; ++mi) {
      const int o = (wm + mi * 16 + fr) * 32 + fq;
      afh[mi] = *(const v8s*)&As0[o];
      afl[mi] = *(const v8s*)&As1[o];
    }
#pragma unroll
    for (int ni = 0; ni < 4; ++ni) {
      const int o = (wn + ni * 16 + fr) * 32 + fq;
      v8s bh = *(const v8s*)&Bs0[o];
      v8s bl = *(const v8s*)&Bs1[o];
#pragma unroll
      for (int mi = 0; mi < 4; ++mi) {
        acc[mi][ni] = __builtin_amdgcn_mfma_f32_16x16x32_bf16(afh[mi], bh, acc[mi][ni], 0, 0, 0);
        acc[mi][ni] = __builtin_amdgcn_mfma_f32_16x16x32_bf16(afh[mi], bl, acc[mi][ni], 0, 0, 0);
        acc[mi][ni] = __builtin_amdgcn_mfma_f32_16x16x32_bf16(afl[mi], bh, acc[mi][ni], 0, 0, 0);
      }
    }
    __syncthreads();
  }
  const int eq = (lane >> 4) * 4;
#pragma unroll
  for (int ni = 0; ni < 4; ++ni) {
    const int col = bn + wn + ni * 16 + fr;
    const float bv = bias[col];
#pragma unroll
    for (int mi = 0; mi < 4; ++mi) {
      const int row0 = bm + wm + mi * 16 + eq;
#pragma unroll
      for (int r = 0; r < 4; ++r) {
        float v = acc[mi][ni][r] + bv;
        if (GELU) v = gelu_f(v);
        C[(size_t)(row0 + r) * N + col] = v;
      }
    }
  }
}

// ---------------- weight transpose + bf16 2-plane split ---------------------
__global__ __launch_bounds__(256)
void wt_k(const float* __restrict__ W, ush* __restrict__ Th, ush* __restrict__ Tl,
          int K, int N)
{
  __shared__ float tile[32][33];
  const int k0 = blockIdx.y * 32, n0 = blockIdx.x * 32;
  const int tx = threadIdx.x & 31, ty = threadIdx.x >> 5;
#pragma unroll
  for (int j = 0; j < 32; j += 8)
    tile[ty + j][tx] = W[(size_t)(k0 + ty + j) * N + n0 + tx];
  __syncthreads();
#pragma unroll
  for (int j = 0; j < 32; j += 8) {
    float v = tile[tx][ty + j];
    ush h = f2bf(v);
    ush l = f2bf(v - bf2f(h));
    size_t o = (size_t)(n0 + ty + j) * K + k0 + tx;
    Th[o] = h;
    Tl[o] = l;
  }
}

// ---------------- weight transpose + bf16 3-plane split ---------------------
__global__ __launch_bounds__(256)
void wt3_k(const float* __restrict__ W, ush* __restrict__ Th,
           ush* __restrict__ Tm, ush* __restrict__ Tl, int K, int N)
{
  __shared__ float tile[32][33];
  const int k0 = blockIdx.y * 32, n0 = blockIdx.x * 32;
  const int tx = threadIdx.x & 31, ty = threadIdx.x >> 5;
#pragma unroll
  for (int j = 0; j < 32; j += 8)
    tile[ty + j][tx] = W[(size_t)(k0 + ty + j) * N + n0 + tx];
  __syncthreads();
#pragma unroll
  for (int j = 0; j < 32; j += 8) {
    float v = tile[tx][ty + j];
    ush h = f2bf(v);
    float r = v - bf2f(h);
    ush m = f2bf_t(r);
    ush l = f2bf_t(r - bf2f(m));
    size_t o = (size_t)(n0 + ty + j) * K + k0 + tx;
    Th[o] = h;
    Tm[o] = m;
    Tl[o] = l;
  }
}

// ---------------- fused flash attention (fp32) ------------------------------
__global__ __launch_bounds__(256)
void attn_k(const float* __restrict__ Q, const float* __restrict__ Km,
            const float* __restrict__ Vm, const float* __restrict__ mask,
            float* __restrict__ O, int mode)
{
  __shared__ float qs[64][68];
  __shared__ float kps[64][68];
  __shared__ float vs[64][68];
  __shared__ float kb[64];
  const int tid = threadIdx.x;
  const int b = blockIdx.x >> 4;
  const int h = blockIdx.x & 15;
  const int q0 = blockIdx.y * 64;
  const int tx = tid & 15;
  const int ty = tid >> 4;
  const int lr = tid >> 2;
  const int lc = (tid & 3) * 16;

  {
    const float* qp = Q + ((size_t)(b * Ss + q0 + lr) * Dd) + h * HDd + lc;
#pragma unroll
    for (int ii = 0; ii < 16; ii += 4) {
      float4 t = *(const float4*)(qp + ii);
      t.x *= 0.125f; t.y *= 0.125f; t.z *= 0.125f; t.w *= 0.125f;
      *(float4*)&qs[lr][lc + ii] = t;
    }
  }
  float m_i[4], l_i[4], o_acc[4][4];
#pragma unroll
  for (int i = 0; i < 4; i++) {
    m_i[i] = -3.0e38f; l_i[i] = 0.f;
#pragma unroll
    for (int j = 0; j < 4; j++) o_acc[i][j] = 0.f;
  }

  for (int kt = 0; kt < Ss / 64; ++kt) {
    __syncthreads();
    const int k0 = kt * 64;
    {
      const float* kp = Km + ((size_t)(b * Ss + k0 + lr) * Dd) + h * HDd + lc;
      const float* vp = Vm + ((size_t)(b * Ss + k0 + lr) * Dd) + h * HDd + lc;
#pragma unroll
      for (int ii = 0; ii < 16; ii += 4) {
        *(float4*)&kps[lr][lc + ii] = *(const float4*)(kp + ii);
        *(float4*)&vs[lr][lc + ii]  = *(const float4*)(vp + ii);
      }
      if (tid < 64) {
        float mv = mask[b * Ss + k0 + tid];
        kb[tid] = mode ? (mv > 0.f ? 0.f : -1.0e9f) : mv;
      }
    }
    __syncthreads();
    float s[4][4];
#pragma unroll
    for (int i = 0; i < 4; i++)
#pragma unroll
      for (int j = 0; j < 4; j++) s[i][j] = 0.f;
    for (int d = 0; d < 64; d += 4) {
      float4 kv[4];
#pragma unroll
      for (int j = 0; j < 4; j++) kv[j] = *(const float4*)&kps[tx * 4 + j][d];
#pragma unroll
      for (int i = 0; i < 4; i++) {
        float4 qv = *(const float4*)&qs[ty * 4 + i][d];
#pragma unroll
        for (int j = 0; j < 4; j++)
          s[i][j] += qv.x * kv[j].x + qv.y * kv[j].y + qv.z * kv[j].z + qv.w * kv[j].w;
      }
    }
#pragma unroll
    for (int i = 0; i < 4; i++)
#pragma unroll
      for (int j = 0; j < 4; j++) s[i][j] += kb[tx * 4 + j];

    float p[4][4];
#pragma unroll
    for (int i = 0; i < 4; i++) {
      float mx = fmaxf(fmaxf(s[i][0], s[i][1]), fmaxf(s[i][2], s[i][3]));
#pragma unroll
      for (int off = 1; off < 16; off <<= 1) mx = fmaxf(mx, __shfl_xor(mx, off, 64));
      float mnew = fmaxf(m_i[i], mx);
      float sum = 0.f;
#pragma unroll
      for (int j = 0; j < 4; j++) { p[i][j] = expf(s[i][j] - mnew); sum += p[i][j]; }
#pragma unroll
      for (int off = 1; off < 16; off <<= 1) sum += __shfl_xor(sum, off, 64);
      float alpha = expf(m_i[i] - mnew);
      l_i[i] = l_i[i] * alpha + sum;
      m_i[i] = mnew;
#pragma unroll
      for (int j = 0; j < 4; j++) o_acc[i][j] *= alpha;
    }
    __syncthreads();
#pragma unroll
    for (int i = 0; i < 4; i++)
      *(float4*)&kps[ty * 4 + i][tx * 4] = make_float4(p[i][0], p[i][1], p[i][2], p[i][3]);
    __syncthreads();
    for (int jj = 0; jj < 64; jj += 4) {
      float pr[4][4];
#pragma unroll
      for (int i = 0; i < 4; i++) {
        float4 pv4 = *(const float4*)&kps[ty * 4 + i][jj];
        pr[i][0] = pv4.x; pr[i][1] = pv4.y; pr[i][2] = pv4.z; pr[i][3] = pv4.w;
      }
#pragma unroll
      for (int kk = 0; kk < 4; ++kk) {
        float4 vv = *(const float4*)&vs[jj + kk][tx * 4];
#pragma unroll
        for (int i = 0; i < 4; i++) {
          o_acc[i][0] = fmaf(pr[i][kk], vv.x, o_acc[i][0]);
          o_acc[i][1] = fmaf(pr[i][kk], vv.y, o_acc[i][1]);
          o_acc[i][2] = fmaf(pr[i][kk], vv.z, o_acc[i][2]);
          o_acc[i][3] = fmaf(pr[i][kk], vv.w, o_acc[i][3]);
        }
      }
    }
  }
#pragma unroll
  for (int i = 0; i < 4; i++) {
    float inv = 1.0f / l_i[i];
    float4 r = make_float4(o_acc[i][0] * inv, o_acc[i][1] * inv,
                           o_acc[i][2] * inv, o_acc[i][3] * inv);
    *(float4*)&O[((size_t)(b * Ss + q0 + ty * 4 + i) * Dd) + h * HDd + tx * 4] = r;
  }
}

// ---------------- fused residual-add + LayerNorm ----------------------------
__global__ __launch_bounds__(256)
void ln_k(const float* __restrict__ X, const float* __restrict__ R,
          const float* __restrict__ g, const float* __restrict__ be,
          float* __restrict__ Out)
{
  __shared__ float red[8];
  const int row = blockIdx.x;
  const int tid = threadIdx.x;
  const int d = tid * 4;
  float4 xv = *(const float4*)(X + (size_t)row * Dd + d);
  float4 rv = *(const float4*)(R + (size_t)row * Dd + d);
  float v0 = xv.x + rv.x, v1 = xv.y + rv.y, v2 = xv.z + rv.z, v3 = xv.w + rv.w;
  float sum = v0 + v1 + v2 + v3;
#pragma unroll
  for (int off = 32; off; off >>= 1) sum += __shfl_xor(sum, off, 64);
  const int wave = tid >> 6, lane = tid & 63;
  if (lane == 0) red[wave] = sum;
  __syncthreads();
  float mean = (red[0] + red[1] + red[2] + red[3]) * (1.0f / Dd);
  float d0 = v0 - mean, d1 = v1 - mean, d2 = v2 - mean, d3 = v3 - mean;
  float ss = d0 * d0 + d1 * d1 + d2 * d2 + d3 * d3;
#pragma unroll
  for (int off = 32; off; off >>= 1) ss += __shfl_xor(ss, off, 64);
  if (lane == 0) red[4 + wave] = ss;
  __syncthreads();
  float var = (red[4] + red[5] + red[6] + red[7]) * (1.0f / Dd);
  float inv = 1.0f / sqrtf(var + 1e-5f);
  float4 gv = *(const float4*)(g + d);
  float4 bv = *(const float4*)(be + d);
  float4 r;
  r.x = d0 * inv * gv.x + bv.x;
  r.y = d1 * inv * gv.y + bv.y;
  r.z = d2 * inv * gv.z + bv.z;
  r.w = d3 * inv * gv.w + bv.w;
  *(float4*)&Out[(size_t)row * Dd + d] = r;
}

// ---------------- per-token sigmoid score -----------------------------------
__global__ __launch_bounds__(256)
void score_k(const float* __restrict__ F, const float* __restrict__ Wsv,
             const float* __restrict__ bs, float* __restrict__ Sout)
{
  const int tok = blockIdx.x * 4 + (threadIdx.x >> 6);
  const int lane = threadIdx.x & 63;
  const float* fp = F + (size_t)tok * Dd;
  float acc = 0.f;
#pragma unroll
  for (int ii = 0; ii < 16; ++ii) {
    int d = lane + ii * 64;
    acc += fp[d] * Wsv[d];
  }
#pragma unroll
  for (int off = 32; off; off >>= 1) acc += __shfl_xor(acc, off, 64);
  if (lane == 0) Sout[tok] = 1.0f / (1.0f + expf(-(acc + bs[0])));
}

// ---------------- per-batch scan: sv, seg, new_mask -------------------------
__global__ __launch_bounds__(256)
void scan_k(const float* __restrict__ sin, const float* __restrict__ mask,
            float* __restrict__ svout, int* __restrict__ segout,
            float* __restrict__ nmask)
{
  __shared__ double sc[256];
  __shared__ float mxs[256];
  const int b = blockIdx.x;
  const int tid = threadIdx.x;
  const int t0 = tid * 4;
  float svl[4], mk[4];
  double loc[4];
  double run = 0.0;
#pragma unroll
  for (int i = 0; i < 4; i++) {
    float s = sin[b * Ss + t0 + i];
    float m = mask[b * Ss + t0 + i];
    float sv = (m > 0.f) ? s : 0.f;
    svl[i] = sv; mk[i] = m;
    run += (double)sv;
    loc[i] = run;
  }
  sc[tid] = run;
  __syncthreads();
  for (int off = 1; off < 256; off <<= 1) {
    double add = (tid >= off) ? sc[tid - off] : 0.0;
    __syncthreads();
    sc[tid] += add;
    __syncthreads();
  }
  double excl = sc[tid] - run;
  float lmax = -1.0f;
#pragma unroll
  for (int i = 0; i < 4; i++) {
    double c = floor(excl + loc[i]);
    int sg = (int)c;
    if (sg < 0) sg = 0;
    if (sg > Ss - 1) sg = Ss - 1;
    svout[b * Ss + t0 + i] = svl[i];
    segout[b * Ss + t0 + i] = sg;
    if (mk[i] > 0.f) lmax = fmaxf(lmax, (float)c);
  }
  mxs[tid] = lmax;
  __syncthreads();
  for (int off = 128; off; off >>= 1) {
    if (tid < off) mxs[tid] = fmaxf(mxs[tid], mxs[tid + off]);
    __syncthreads();
  }
  float mseg = mxs[0];
#pragma unroll
  for (int i = 0; i < 4; i++)
    nmask[b * Ss + t0 + i] = ((float)(t0 + i) <= mseg) ? 1.0f : 0.0f;
}

// ---------------- weighted segment scatter-add ------------------------------
__global__ __launch_bounds__(256)
void scatter_k(const float* __restrict__ X, const float* __restrict__ sv,
               const int* __restrict__ seg, float* __restrict__ pooled)
{
  const int tok = blockIdx.x;
  const float w = sv[tok];
  if (w == 0.f) return;
  const int b = tok >> 10;
  const int sg = seg[tok];
  const int d = threadIdx.x * 4;
  float4 xv = *(const float4*)(X + (size_t)tok * Dd + d);
  float* pp = pooled + ((size_t)(b * Ss + sg)) * Dd + d;
  atomicAdd(pp + 0, xv.x * w);
  atomicAdd(pp + 1, xv.y * w);
  atomicAdd(pp + 2, xv.z * w);
  atomicAdd(pp + 3, xv.w * w);
}

static inline void launch_gemm6(const float* A, const ush* Bh, const ush* Bm,
                                const ush* Bl, const float* bias, float* C,
                                int M, int N, int K, bool gelu, hipStream_t st)
{
  dim3 g(N / 128, M / 128), blk(256);
  if (gelu) hipLaunchKernelGGL((gemm6_k<1>), g, blk, 0, st, A, Bh, Bm, Bl, bias, C, M, N, K);
  else      hipLaunchKernelGGL((gemm6_k<0>), g, blk, 0, st, A, Bh, Bm, Bl, bias, C, M, N, K);
}

static inline void launch_gemm3(const float* A, const ush* Bh, const ush* Bl,
                                const float* bias, float* C, int M, int N, int K,
                                bool gelu, hipStream_t st)
{
  dim3 g(N / 128, M / 128), blk(256);
  if (gelu) hipLaunchKernelGGL((gemm3_k<1>), g, blk, 0, st, A, Bh, Bl, bias, C, M, N, K);
  else      hipLaunchKernelGGL((gemm3_k<0>), g, blk, 0, st, A, Bh, Bl, bias, C, M, N, K);
}

extern "C" void kernel_launch(void* const* d_in, const int* in_sizes, int n_in,
                              void* d_out, int out_size, void* d_ws, size_t ws_size,
                              hipStream_t stream)
{
  const float* x     = (const float*)d_in[0];
  const float* masks = (const float*)d_in[1];
  const float* Wq  = (const float*)d_in[2];
  const float* bq  = (const float*)d_in[3];
  const float* Wk  = (const float*)d_in[4];
  const float* bk  = (const float*)d_in[5];
  const float* Wv  = (const float*)d_in[6];
  const float* bv  = (const float*)d_in[7];
  const float* Wo  = (const float*)d_in[8];
  const float* bo  = (const float*)d_in[9];
  const float* g1  = (const float*)d_in[10];
  const float* be1 = (const float*)d_in[11];
  const float* g2  = (const float*)d_in[12];
  const float* be2 = (const float*)d_in[13];
  const float* W1  = (const float*)d_in[14];
  const float* bf1 = (const float*)d_in[15];
  const float* W2  = (const float*)d_in[16];
  const float* bf2 = (const float*)d_in[17];
  const float* Wsp = (const float*)d_in[18];
  const float* bs  = (const float*)d_in[19];
  const float* P1  = (const float*)d_in[20];
  const float* bp1 = (const float*)d_in[21];
  const float* P2  = (const float*)d_in[22];
  const float* bp2 = (const float*)d_in[23];

  // ---- workspace: [W3enc 24M ush = 48MB][u0..u5 6x16.78MB][smalls] = 148.8MB
  // Encoder rotation (verified liveness):
  //  pass1 (xin=x):   q=u0 k=u1 v=u2 ao=u3 t1=u4 hb=u5 ffh=u0u1 t1b=u4 feat1=u2
  //  pass2 (xin=u2):  q=u0 k=u1 v=u3 ao=u4 t1=u5 hb=u3 ffh=u4u5 t1b=u0 feat2=u1
  //  post: pooled=u0, hid=u2..u5, P1t over W3[0..8M], P2t over d_ws[0..32M ush]
  //  (W3 dead + u0 dead-after-P1; u1 untouched; hid starts at 48+2*16.78 MB).
  const size_t UW = (size_t)Dd * Dd;        // 1,048,576
  const size_t ND = (size_t)NTOK * Dd;      // 4,194,304 floats
  ush* w3 = (ush*)d_ws;
  ush *wqh = w3 + 0*UW,  *wqm = w3 + 1*UW,  *wql = w3 + 2*UW;
  ush *wkh = w3 + 3*UW,  *wkm = w3 + 4*UW,  *wkl = w3 + 5*UW;
  ush *wvh = w3 + 6*UW,  *wvm = w3 + 7*UW,  *wvl = w3 + 8*UW;
  ush *woh = w3 + 9*UW,  *wom = w3 + 10*UW, *wol = w3 + 11*UW;
  ush *w1h = w3 + 12*UW, *w1m = w3 + 14*UW, *w1l = w3 + 16*UW;  // 2*UW each
  ush *w2h = w3 + 18*UW, *w2m = w3 + 20*UW, *w2l = w3 + 22*UW;  // 2*UW each
  float* ub = (float*)(w3 + 24*UW);
  float* u0 = ub + 0 * ND;
  float* u1 = ub + 1 * ND;
  float* u2 = ub + 2 * ND;
  float* u3 = ub + 3 * ND;
  float* u4 = ub + 4 * ND;
  float* u5 = ub + 5 * ND;
  float* sbuf = ub + 6 * ND;
  float* svb  = sbuf + NTOK;
  int*   segb = (int*)(sbuf + 2 * NTOK);

  float* pooled = u0;
  float* hid = u2;                   // spans u2..u5
  ush*   p1h = w3;                   // 4M ush
  ush*   p1l = w3 + 4*UW;
  ush*   p2h = (ush*)d_ws;           // 16M ush
  ush*   p2l = p2h + (size_t)HIDh * HIDh;
  float* outp = (float*)d_out;
  float* nmask = outp + (size_t)NTOK * HIDh;

  // ---- split encoder weights (3-plane, transposed) -------------------------
  hipLaunchKernelGGL(wt3_k, dim3(Dd/32, Dd/32), dim3(256), 0, stream, Wq, wqh, wqm, wql, Dd, Dd);
  hipLaunchKernelGGL(wt3_k, dim3(Dd/32, Dd/32), dim3(256), 0, stream, Wk, wkh, wkm, wkl, Dd, Dd);
  hipLaunchKernelGGL(wt3_k, dim3(Dd/32, Dd/32), dim3(256), 0, stream, Wv, wvh, wvm, wvl, Dd, Dd);
  hipLaunchKernelGGL(wt3_k, dim3(Dd/32, Dd/32), dim3(256), 0, stream, Wo, woh, wom, wol, Dd, Dd);
  hipLaunchKernelGGL(wt3_k, dim3(FFf/32, Dd/32), dim3(256), 0, stream, W1, w1h, w1m, w1l, Dd, FFf);
  hipLaunchKernelGGL(wt3_k, dim3(Dd/32, FFf/32), dim3(256), 0, stream, W2, w2h, w2m, w2l, FFf, Dd);

  auto enc = [&](const float* xin, float* q, float* k, float* v, float* ao,
                 float* t1, float* hb, float* ffh, float* t1b, float* fout,
                 int mode) {
    launch_gemm6(xin, wqh, wqm, wql, bq, q, NTOK, Dd, Dd, false, stream);
    launch_gemm6(xin, wkh, wkm, wkl, bk, k, NTOK, Dd, Dd, false, stream);
    launch_gemm6(xin, wvh, wvm, wvl, bv, v, NTOK, Dd, Dd, false, stream);
    hipLaunchKernelGGL(attn_k, dim3(Bb * Hh, Ss / 64), dim3(256), 0, stream,
                       q, k, v, masks, ao, mode);
    launch_gemm6(ao, woh, wom, wol, bo, t1, NTOK, Dd, Dd, false, stream);
    hipLaunchKernelGGL(ln_k, dim3(NTOK), dim3(256), 0, stream, t1, xin, g1, be1, hb);
    launch_gemm6(hb, w1h, w1m, w1l, bf1, ffh, NTOK, FFf, Dd, true, stream);
    launch_gemm6(ffh, w2h, w2m, w2l, bf2, t1b, NTOK, Dd, FFf, false, stream);
    hipLaunchKernelGGL(ln_k, dim3(NTOK), dim3(256), 0, stream, t1b, hb, g2, be2, fout);
  };

  // pass 1 (float mask ADDED): xin=x
  enc(x,  u0, u1, u2, u3, u4, u5, u0 /*ffh=u0u1*/, u4, u2 /*feat1*/, 0);
  // pass 2 (0/-1e9 mask): xin=u2
  enc(u2, u0, u1, u3, u4, u5, u3, u4 /*ffh=u4u5*/, u0, u1 /*feat2*/, 1);

  hipLaunchKernelGGL(score_k, dim3(NTOK / 4), dim3(256), 0, stream, u1, Wsp, bs, sbuf);
  hipLaunchKernelGGL(scan_k, dim3(Bb), dim3(256), 0, stream, sbuf, masks, svb, segb, nmask);
  hipMemsetAsync(pooled, 0, ND * sizeof(float), stream);
  hipLaunchKernelGGL(scatter_k, dim3(NTOK), dim3(256), 0, stream, x, svb, segb, pooled);

  // projector (bf16x3 — downstream of the floor)
  hipLaunchKernelGGL(wt_k, dim3(HIDh / 32, Dd / 32), dim3(256), 0, stream, P1, p1h, p1l, Dd, HIDh);
  launch_gemm3(pooled, p1h, p1l, bp1, hid, NTOK, HIDh, Dd, true, stream);
  hipLaunchKernelGGL(wt_k, dim3(HIDh / 32, HIDh / 32), dim3(256), 0, stream, P2, p2h, p2l, HIDh, HIDh);
  launch_gemm3(hid, p2h, p2l, bp2, outp, NTOK, HIDh, HIDh, false, stream);
}

// Round 5
// 2227.569 us; speedup vs baseline: 2.3423x; 1.1516x over previous
//
#include <hip/hip_runtime.h>

#define Bb 4
#define Ss 1024
#define Dd 1024
#define Hh 16
#define HDd 64
#define FFf 2048
#define HIDh 4096
#define NTOK (Bb*Ss)
#define QKVN 3072

typedef unsigned short ush;
typedef short v8s __attribute__((ext_vector_type(8)));
typedef float v4f __attribute__((ext_vector_type(4)));

__device__ __forceinline__ float gelu_f(float x) {
  return 0.5f * x * (1.0f + erff(x * 0.70710678118654752f));
}
__device__ __forceinline__ ush f2bf(float x) {              // RNE
  unsigned int u = __float_as_uint(x);
  u += 0x7FFFu + ((u >> 16) & 1u);
  return (ush)(u >> 16);
}
__device__ __forceinline__ ush f2bf_t(float x) {            // truncate
  return (ush)(__float_as_uint(x) >> 16);
}
__device__ __forceinline__ float bf2f(ush h) {
  return __uint_as_float(((unsigned int)h) << 16);
}
__device__ __forceinline__ void gload16(const void* g, void* l) {
  __builtin_amdgcn_global_load_lds(
      (const __attribute__((address_space(1))) unsigned int*)g,
      (__attribute__((address_space(3))) unsigned int*)l, 16, 0, 0);
}

// ---------------- bf16x6 split GEMM (fp32-fidelity, encoder path) -----------
// BN=128: 128x128 tile, 4 waves as 2x2 of 64x64. BN=64: 128x64 tile, waves
// 2x2 of 64x32 (doubles grid for N=1024 GEMMs: 256->512 blocks).
template<int GELU, int BN>
__global__ __launch_bounds__(256)
void gemm6_k(const float* __restrict__ A, const ush* __restrict__ Bh,
             const ush* __restrict__ Bm, const ush* __restrict__ Bl,
             const float* __restrict__ bias, float* __restrict__ C,
             int M, int N, int K)
{
  constexpr int NI = BN / 32;                 // n-tiles per wave
  __shared__ __align__(16) ush As0[128 * 32];
  __shared__ __align__(16) ush As1[128 * 32];
  __shared__ __align__(16) ush As2[128 * 32];
  __shared__ __align__(16) ush Bs0[BN * 32];
  __shared__ __align__(16) ush Bs1[BN * 32];
  __shared__ __align__(16) ush Bs2[BN * 32];
  const int tid = threadIdx.x;
  const int lane = tid & 63, wave = tid >> 6;
  const int bm = blockIdx.y * 128, bn = blockIdx.x * BN;
  const int wm = (wave & 1) * 64, wn = (wave >> 1) * (BN / 2);

  v4f acc[4][NI] = {};

  const int ma = tid >> 3;             // 0..31
  const int ka = (tid & 7) * 4;        // 0..28
  const float* Ap = A + (size_t)(bm + ma) * K + ka;

  // B staging: each wave covers BN/4 n-rows per plane in BN/64 16-row chunks
  const int nb = bn + wave * (BN / 4) + (lane >> 2);
  const int kb = (lane & 3) * 8;
  const ush* gh0 = Bh + (size_t)nb * K + kb;
  const ush* gm0 = Bm + (size_t)nb * K + kb;
  const ush* gl0 = Bl + (size_t)nb * K + kb;
  const size_t row16 = (size_t)16 * K;
  ush* lbh = &Bs0[wave * (BN / 4) * 32];
  ush* lbm = &Bs1[wave * (BN / 4) * 32];
  ush* lbl = &Bs2[wave * (BN / 4) * 32];

  const int fr = lane & 15;
  const int fq = (lane >> 4) * 8;

  for (int k0 = 0; k0 < K; k0 += 32) {
#pragma unroll
    for (int c = 0; c < BN / 64; ++c) {
      gload16(gh0 + c * row16 + k0, lbh + c * 512);
      gload16(gm0 + c * row16 + k0, lbm + c * 512);
      gload16(gl0 + c * row16 + k0, lbl + c * 512);
    }
#pragma unroll
    for (int p = 0; p < 4; ++p) {
      float4 v = *(const float4*)(Ap + (size_t)p * 32 * K + k0);
      ushort4 h, m, l;
      float r;
      h.x = f2bf(v.x); r = v.x - bf2f(h.x); m.x = f2bf_t(r); l.x = f2bf_t(r - bf2f(m.x));
      h.y = f2bf(v.y); r = v.y - bf2f(h.y); m.y = f2bf_t(r); l.y = f2bf_t(r - bf2f(m.y));
      h.z = f2bf(v.z); r = v.z - bf2f(h.z); m.z = f2bf_t(r); l.z = f2bf_t(r - bf2f(m.z));
      h.w = f2bf(v.w); r = v.w - bf2f(h.w); m.w = f2bf_t(r); l.w = f2bf_t(r - bf2f(m.w));
      const int off = (ma + p * 32) * 32 + ka;
      *(ushort4*)&As0[off] = h;
      *(ushort4*)&As1[off] = m;
      *(ushort4*)&As2[off] = l;
    }
    __syncthreads();
    v8s ah[4], am[4], al[4];
#pragma unroll
    for (int mi = 0; mi < 4; ++mi) {
      const int o = (wm + mi * 16 + fr) * 32 + fq;
      ah[mi] = *(const v8s*)&As0[o];
      am[mi] = *(const v8s*)&As1[o];
      al[mi] = *(const v8s*)&As2[o];
    }
#pragma unroll
    for (int ni = 0; ni < NI; ++ni) {
      const int o = (wn + ni * 16 + fr) * 32 + fq;
      v8s bh = *(const v8s*)&Bs0[o];
      v8s bm_ = *(const v8s*)&Bs1[o];
      v8s bl = *(const v8s*)&Bs2[o];
#pragma unroll
      for (int mi = 0; mi < 4; ++mi) {
        acc[mi][ni] = __builtin_amdgcn_mfma_f32_16x16x32_bf16(ah[mi], bh,  acc[mi][ni], 0, 0, 0);
        acc[mi][ni] = __builtin_amdgcn_mfma_f32_16x16x32_bf16(ah[mi], bm_, acc[mi][ni], 0, 0, 0);
        acc[mi][ni] = __builtin_amdgcn_mfma_f32_16x16x32_bf16(am[mi], bh,  acc[mi][ni], 0, 0, 0);
        acc[mi][ni] = __builtin_amdgcn_mfma_f32_16x16x32_bf16(ah[mi], bl,  acc[mi][ni], 0, 0, 0);
        acc[mi][ni] = __builtin_amdgcn_mfma_f32_16x16x32_bf16(al[mi], bh,  acc[mi][ni], 0, 0, 0);
        acc[mi][ni] = __builtin_amdgcn_mfma_f32_16x16x32_bf16(am[mi], bm_, acc[mi][ni], 0, 0, 0);
      }
    }
    __syncthreads();
  }
  const int eq = (lane >> 4) * 4;
#pragma unroll
  for (int ni = 0; ni < NI; ++ni) {
    const int col = bn + wn + ni * 16 + fr;
    const float bv = bias[col];
#pragma unroll
    for (int mi = 0; mi < 4; ++mi) {
      const int row0 = bm + wm + mi * 16 + eq;
#pragma unroll
      for (int r = 0; r < 4; ++r) {
        float v = acc[mi][ni][r] + bv;
        if (GELU) v = gelu_f(v);
        C[(size_t)(row0 + r) * N + col] = v;
      }
    }
  }
}

// ---------------- bf16x3 GEMM + inactive-block skip (projector) -------------
// Blocks whose 128 rows all lie past nact[batch] write cvec instead (pooled
// rows there are zero -> output is the constant vector).
template<int GELU>
__global__ __launch_bounds__(256)
void gemm3s_k(const float* __restrict__ A, const ush* __restrict__ Bh,
              const ush* __restrict__ Bl, const float* __restrict__ bias,
              float* __restrict__ C, int M, int N, int K,
              const int* __restrict__ nact, const float* __restrict__ cvec)
{
  const int tid = threadIdx.x;
  const int bm = blockIdx.y * 128, bn = blockIdx.x * 128;
  if ((bm & (Ss - 1)) >= nact[bm >> 10]) {
    const int col = bn + (tid & 31) * 4;
    float4 cv = *(const float4*)&cvec[col];
#pragma unroll
    for (int i = 0; i < 16; ++i) {
      int row = bm + (tid >> 5) + i * 8;
      *(float4*)&C[(size_t)row * N + col] = cv;
    }
    return;
  }
  __shared__ __align__(16) ush As0[128 * 32];
  __shared__ __align__(16) ush As1[128 * 32];
  __shared__ __align__(16) ush Bs0[128 * 32];
  __shared__ __align__(16) ush Bs1[128 * 32];
  const int lane = tid & 63, wave = tid >> 6;
  const int wm = (wave & 1) * 64, wn = (wave >> 1) * 64;

  v4f acc[4][4] = {};

  const int ma = tid >> 3;
  const int ka = (tid & 7) * 4;
  const float* Ap = A + (size_t)(bm + ma) * K + ka;

  const int nb = bn + wave * 32 + (lane >> 2);
  const int kb = (lane & 3) * 8;
  const ush* g0h = Bh + (size_t)nb * K + kb;
  const ush* g1h = g0h + (size_t)16 * K;
  const ush* g0l = Bl + (size_t)nb * K + kb;
  const ush* g1l = g0l + (size_t)16 * K;
  ush* lb0h = &Bs0[wave * 1024];
  ush* lb1h = &Bs0[wave * 1024 + 512];
  ush* lb0l = &Bs1[wave * 1024];
  ush* lb1l = &Bs1[wave * 1024 + 512];

  const int fr = lane & 15;
  const int fq = (lane >> 4) * 8;

  for (int k0 = 0; k0 < K; k0 += 32) {
    gload16(g0h + k0, lb0h);
    gload16(g1h + k0, lb1h);
    gload16(g0l + k0, lb0l);
    gload16(g1l + k0, lb1l);
#pragma unroll
    for (int p = 0; p < 4; ++p) {
      float4 v = *(const float4*)(Ap + (size_t)p * 32 * K + k0);
      ushort4 h, l;
      h.x = f2bf(v.x); l.x = f2bf(v.x - bf2f(h.x));
      h.y = f2bf(v.y); l.y = f2bf(v.y - bf2f(h.y));
      h.z = f2bf(v.z); l.z = f2bf(v.z - bf2f(h.z));
      h.w = f2bf(v.w); l.w = f2bf(v.w - bf2f(h.w));
      const int off = (ma + p * 32) * 32 + ka;
      *(ushort4*)&As0[off] = h;
      *(ushort4*)&As1[off] = l;
    }
    __syncthreads();
    v8s afh[4], afl[4];
#pragma unroll
    for (int mi = 0; mi < 4; ++mi) {
      const int o = (wm + mi * 16 + fr) * 32 + fq;
      afh[mi] = *(const v8s*)&As0[o];
      afl[mi] = *(const v8s*)&As1[o];
    }
#pragma unroll
    for (int ni = 0; ni < 4; ++ni) {
      const int o = (wn + ni * 16 + fr) * 32 + fq;
      v8s bh = *(const v8s*)&Bs0[o];
      v8s bl = *(const v8s*)&Bs1[o];
#pragma unroll
      for (int mi = 0; mi < 4; ++mi) {
        acc[mi][ni] = __builtin_amdgcn_mfma_f32_16x16x32_bf16(afh[mi], bh, acc[mi][ni], 0, 0, 0);
        acc[mi][ni] = __builtin_amdgcn_mfma_f32_16x16x32_bf16(afh[mi], bl, acc[mi][ni], 0, 0, 0);
        acc[mi][ni] = __builtin_amdgcn_mfma_f32_16x16x32_bf16(afl[mi], bh, acc[mi][ni], 0, 0, 0);
      }
    }
    __syncthreads();
  }
  const int eq = (lane >> 4) * 4;
#pragma unroll
  for (int ni = 0; ni < 4; ++ni) {
    const int col = bn + wn + ni * 16 + fr;
    const float bv = bias[col];
#pragma unroll
    for (int mi = 0; mi < 4; ++mi) {
      const int row0 = bm + wm + mi * 16 + eq;
#pragma unroll
      for (int r = 0; r < 4; ++r) {
        float v = acc[mi][ni][r] + bv;
        if (GELU) v = gelu_f(v);
        C[(size_t)(row0 + r) * N + col] = v;
      }
    }
  }
}

// ---------------- weight transpose + split kernels --------------------------
__global__ __launch_bounds__(256)
void wt_k(const float* __restrict__ W, ush* __restrict__ Th, ush* __restrict__ Tl,
          int K, int N)
{
  __shared__ float tile[32][33];
  const int k0 = blockIdx.y * 32, n0 = blockIdx.x * 32;
  const int tx = threadIdx.x & 31, ty = threadIdx.x >> 5;
#pragma unroll
  for (int j = 0; j < 32; j += 8)
    tile[ty + j][tx] = W[(size_t)(k0 + ty + j) * N + n0 + tx];
  __syncthreads();
#pragma unroll
  for (int j = 0; j < 32; j += 8) {
    float v = tile[tx][ty + j];
    ush h = f2bf(v);
    ush l = f2bf(v - bf2f(h));
    size_t o = (size_t)(n0 + ty + j) * K + k0 + tx;
    Th[o] = h;
    Tl[o] = l;
  }
}

__global__ __launch_bounds__(256)
void wt3_k(const float* __restrict__ W, ush* __restrict__ Th,
           ush* __restrict__ Tm, ush* __restrict__ Tl, int K, int N)
{
  __shared__ float tile[32][33];
  const int k0 = blockIdx.y * 32, n0 = blockIdx.x * 32;
  const int tx = threadIdx.x & 31, ty = threadIdx.x >> 5;
#pragma unroll
  for (int j = 0; j < 32; j += 8)
    tile[ty + j][tx] = W[(size_t)(k0 + ty + j) * N + n0 + tx];
  __syncthreads();
#pragma unroll
  for (int j = 0; j < 32; j += 8) {
    float v = tile[tx][ty + j];
    ush h = f2bf(v);
    float r = v - bf2f(h);
    ush m = f2bf_t(r);
    ush l = f2bf_t(r - bf2f(m));
    size_t o = (size_t)(n0 + ty + j) * K + k0 + tx;
    Th[o] = h;
    Tm[o] = m;
    Tl[o] = l;
  }
}

// ---------------- fused flash attention (fp32, qkv-packed input) ------------
// QKV layout [B*S][3072]: cols 0..1023 = Q, 1024..2047 = K, 2048..3071 = V.
__global__ __launch_bounds__(256)
void attn_k(const float* __restrict__ QKV, const float* __restrict__ mask,
            float* __restrict__ O, int mode)
{
  __shared__ float qs[64][68];
  __shared__ float kps[64][68];
  __shared__ float vs[64][68];
  __shared__ float kb[64];
  const int tid = threadIdx.x;
  const int b = blockIdx.x >> 4;
  const int h = blockIdx.x & 15;
  const int q0 = blockIdx.y * 64;
  const int tx = tid & 15;
  const int ty = tid >> 4;
  const int lr = tid >> 2;
  const int lc = (tid & 3) * 16;

  {
    const float* qp = QKV + ((size_t)(b * Ss + q0 + lr) * QKVN) + h * HDd + lc;
#pragma unroll
    for (int ii = 0; ii < 16; ii += 4) {
      float4 t = *(const float4*)(qp + ii);
      t.x *= 0.125f; t.y *= 0.125f; t.z *= 0.125f; t.w *= 0.125f;
      *(float4*)&qs[lr][lc + ii] = t;
    }
  }
  float m_i[4], l_i[4], o_acc[4][4];
#pragma unroll
  for (int i = 0; i < 4; i++) {
    m_i[i] = -3.0e38f; l_i[i] = 0.f;
#pragma unroll
    for (int j = 0; j < 4; j++) o_acc[i][j] = 0.f;
  }

  for (int kt = 0; kt < Ss / 64; ++kt) {
    __syncthreads();
    const int k0 = kt * 64;
    {
      const float* kp = QKV + 1024 + ((size_t)(b * Ss + k0 + lr) * QKVN) + h * HDd + lc;
      const float* vp = QKV + 2048 + ((size_t)(b * Ss + k0 + lr) * QKVN) + h * HDd + lc;
#pragma unroll
      for (int ii = 0; ii < 16; ii += 4) {
        *(float4*)&kps[lr][lc + ii] = *(const float4*)(kp + ii);
        *(float4*)&vs[lr][lc + ii]  = *(const float4*)(vp + ii);
      }
      if (tid < 64) {
        float mv = mask[b * Ss + k0 + tid];
        kb[tid] = mode ? (mv > 0.f ? 0.f : -1.0e9f) : mv;
      }
    }
    __syncthreads();
    float s[4][4];
#pragma unroll
    for (int i = 0; i < 4; i++)
#pragma unroll
      for (int j = 0; j < 4; j++) s[i][j] = 0.f;
    for (int d = 0; d < 64; d += 4) {
      float4 kv[4];
#pragma unroll
      for (int j = 0; j < 4; j++) kv[j] = *(const float4*)&kps[tx * 4 + j][d];
#pragma unroll
      for (int i = 0; i < 4; i++) {
        float4 qv = *(const float4*)&qs[ty * 4 + i][d];
#pragma unroll
        for (int j = 0; j < 4; j++)
          s[i][j] += qv.x * kv[j].x + qv.y * kv[j].y + qv.z * kv[j].z + qv.w * kv[j].w;
      }
    }
#pragma unroll
    for (int i = 0; i < 4; i++)
#pragma unroll
      for (int j = 0; j < 4; j++) s[i][j] += kb[tx * 4 + j];

    float p[4][4];
#pragma unroll
    for (int i = 0; i < 4; i++) {
      float mx = fmaxf(fmaxf(s[i][0], s[i][1]), fmaxf(s[i][2], s[i][3]));
#pragma unroll
      for (int off = 1; off < 16; off <<= 1) mx = fmaxf(mx, __shfl_xor(mx, off, 64));
      float mnew = fmaxf(m_i[i], mx);
      float sum = 0.f;
#pragma unroll
      for (int j = 0; j < 4; j++) { p[i][j] = expf(s[i][j] - mnew); sum += p[i][j]; }
#pragma unroll
      for (int off = 1; off < 16; off <<= 1) sum += __shfl_xor(sum, off, 64);
      float alpha = expf(m_i[i] - mnew);
      l_i[i] = l_i[i] * alpha + sum;
      m_i[i] = mnew;
#pragma unroll
      for (int j = 0; j < 4; j++) o_acc[i][j] *= alpha;
    }
    __syncthreads();
#pragma unroll
    for (int i = 0; i < 4; i++)
      *(float4*)&kps[ty * 4 + i][tx * 4] = make_float4(p[i][0], p[i][1], p[i][2], p[i][3]);
    __syncthreads();
    for (int jj = 0; jj < 64; jj += 4) {
      float pr[4][4];
#pragma unroll
      for (int i = 0; i < 4; i++) {
        float4 pv4 = *(const float4*)&kps[ty * 4 + i][jj];
        pr[i][0] = pv4.x; pr[i][1] = pv4.y; pr[i][2] = pv4.z; pr[i][3] = pv4.w;
      }
#pragma unroll
      for (int kk = 0; kk < 4; ++kk) {
        float4 vv = *(const float4*)&vs[jj + kk][tx * 4];
#pragma unroll
        for (int i = 0; i < 4; i++) {
          o_acc[i][0] = fmaf(pr[i][kk], vv.x, o_acc[i][0]);
          o_acc[i][1] = fmaf(pr[i][kk], vv.y, o_acc[i][1]);
          o_acc[i][2] = fmaf(pr[i][kk], vv.z, o_acc[i][2]);
          o_acc[i][3] = fmaf(pr[i][kk], vv.w, o_acc[i][3]);
        }
      }
    }
  }
#pragma unroll
  for (int i = 0; i < 4; i++) {
    float inv = 1.0f / l_i[i];
    float4 r = make_float4(o_acc[i][0] * inv, o_acc[i][1] * inv,
                           o_acc[i][2] * inv, o_acc[i][3] * inv);
    *(float4*)&O[((size_t)(b * Ss + q0 + ty * 4 + i) * Dd) + h * HDd + tx * 4] = r;
  }
}

// ---------------- fused residual-add + LayerNorm ----------------------------
__global__ __launch_bounds__(256)
void ln_k(const float* __restrict__ X, const float* __restrict__ R,
          const float* __restrict__ g, const float* __restrict__ be,
          float* __restrict__ Out)
{
  __shared__ float red[8];
  const int row = blockIdx.x;
  const int tid = threadIdx.x;
  const int d = tid * 4;
  float4 xv = *(const float4*)(X + (size_t)row * Dd + d);
  float4 rv = *(const float4*)(R + (size_t)row * Dd + d);
  float v0 = xv.x + rv.x, v1 = xv.y + rv.y, v2 = xv.z + rv.z, v3 = xv.w + rv.w;
  float sum = v0 + v1 + v2 + v3;
#pragma unroll
  for (int off = 32; off; off >>= 1) sum += __shfl_xor(sum, off, 64);
  const int wave = tid >> 6, lane = tid & 63;
  if (lane == 0) red[wave] = sum;
  __syncthreads();
  float mean = (red[0] + red[1] + red[2] + red[3]) * (1.0f / Dd);
  float d0 = v0 - mean, d1 = v1 - mean, d2 = v2 - mean, d3 = v3 - mean;
  float ss = d0 * d0 + d1 * d1 + d2 * d2 + d3 * d3;
#pragma unroll
  for (int off = 32; off; off >>= 1) ss += __shfl_xor(ss, off, 64);
  if (lane == 0) red[4 + wave] = ss;
  __syncthreads();
  float var = (red[4] + red[5] + red[6] + red[7]) * (1.0f / Dd);
  float inv = 1.0f / sqrtf(var + 1e-5f);
  float4 gv = *(const float4*)(g + d);
  float4 bv = *(const float4*)(be + d);
  float4 r;
  r.x = d0 * inv * gv.x + bv.x;
  r.y = d1 * inv * gv.y + bv.y;
  r.z = d2 * inv * gv.z + bv.z;
  r.w = d3 * inv * gv.w + bv.w;
  *(float4*)&Out[(size_t)row * Dd + d] = r;
}

// ---------------- per-token sigmoid score -----------------------------------
__global__ __launch_bounds__(256)
void score_k(const float* __restrict__ F, const float* __restrict__ Wsv,
             const float* __restrict__ bs, float* __restrict__ Sout)
{
  const int tok = blockIdx.x * 4 + (threadIdx.x >> 6);
  const int lane = threadIdx.x & 63;
  const float* fp = F + (size_t)tok * Dd;
  float acc = 0.f;
#pragma unroll
  for (int ii = 0; ii < 16; ++ii) {
    int d = lane + ii * 64;
    acc += fp[d] * Wsv[d];
  }
#pragma unroll
  for (int off = 32; off; off >>= 1) acc += __shfl_xor(acc, off, 64);
  if (lane == 0) Sout[tok] = 1.0f / (1.0f + expf(-(acc + bs[0])));
}

// ---------------- per-batch scan: sv, seg, new_mask, nact -------------------
__global__ __launch_bounds__(256)
void scan_k(const float* __restrict__ sin, const float* __restrict__ mask,
            float* __restrict__ svout, int* __restrict__ segout,
            float* __restrict__ nmask, int* __restrict__ nact)
{
  __shared__ double sc[256];
  __shared__ float mxs[256];
  const int b = blockIdx.x;
  const int tid = threadIdx.x;
  const int t0 = tid * 4;
  float svl[4], mk[4];
  double loc[4];
  double run = 0.0;
#pragma unroll
  for (int i = 0; i < 4; i++) {
    float s = sin[b * Ss + t0 + i];
    float m = mask[b * Ss + t0 + i];
    float sv = (m > 0.f) ? s : 0.f;
    svl[i] = sv; mk[i] = m;
    run += (double)sv;
    loc[i] = run;
  }
  sc[tid] = run;
  __syncthreads();
  for (int off = 1; off < 256; off <<= 1) {
    double add = (tid >= off) ? sc[tid - off] : 0.0;
    __syncthreads();
    sc[tid] += add;
    __syncthreads();
  }
  double excl = sc[tid] - run;
  float lmax = -1.0f;
#pragma unroll
  for (int i = 0; i < 4; i++) {
    double c = floor(excl + loc[i]);
    int sg = (int)c;
    if (sg < 0) sg = 0;
    if (sg > Ss - 1) sg = Ss - 1;
    svout[b * Ss + t0 + i] = svl[i];
    segout[b * Ss + t0 + i] = sg;
    if (mk[i] > 0.f) lmax = fmaxf(lmax, (float)c);
  }
  mxs[tid] = lmax;
  __syncthreads();
  for (int off = 128; off; off >>= 1) {
    if (tid < off) mxs[tid] = fmaxf(mxs[tid], mxs[tid + off]);
    __syncthreads();
  }
  float mseg = mxs[0];
  if (tid == 0) {
    int na = (int)mseg + 1;
    if (na < 1) na = 1;
    if (na > Ss) na = Ss;
    nact[b] = na;
  }
#pragma unroll
  for (int i = 0; i < 4; i++)
    nmask[b * Ss + t0 + i] = ((float)(t0 + i) <= mseg) ? 1.0f : 0.0f;
}

// ---------------- weighted segment scatter-add ------------------------------
__global__ __launch_bounds__(256)
void scatter_k(const float* __restrict__ X, const float* __restrict__ sv,
               const int* __restrict__ seg, float* __restrict__ pooled)
{
  const int tok = blockIdx.x;
  const float w = sv[tok];
  if (w == 0.f) return;
  const int b = tok >> 10;
  const int sg = seg[tok];
  const int d = threadIdx.x * 4;
  float4 xv = *(const float4*)(X + (size_t)tok * Dd + d);
  float* pp = pooled + ((size_t)(b * Ss + sg)) * Dd + d;
  atomicAdd(pp + 0, xv.x * w);
  atomicAdd(pp + 1, xv.y * w);
  atomicAdd(pp + 2, xv.z * w);
  atomicAdd(pp + 3, xv.w * w);
}

// ---------------- small helpers: bias concat, const rows --------------------
__global__ __launch_bounds__(256)
void bcat_k(const float* __restrict__ bq, const float* __restrict__ bk,
            const float* __restrict__ bv, float* __restrict__ out)
{
  int i = blockIdx.x * 256 + threadIdx.x;     // 3072 total
  float v = (i < 1024) ? bq[i] : (i < 2048) ? bk[i - 1024] : bv[i - 2048];
  out[i] = v;
}
__global__ __launch_bounds__(256)
void cv1_k(const float* __restrict__ bp1, float* __restrict__ cv1)
{
  int i = blockIdx.x * 256 + threadIdx.x;     // 4096
  cv1[i] = gelu_f(bp1[i]);
}
// cv2[col] = sum_k cv1[k]*(P2T_h+P2T_l)[col][k] + bp2[col]; 4 cols/block
__global__ __launch_bounds__(256)
void cv2_k(const float* __restrict__ cv1, const ush* __restrict__ p2h,
           const ush* __restrict__ p2l, const float* __restrict__ bp2,
           float* __restrict__ cv2)
{
  const int col = blockIdx.x * 4 + (threadIdx.x >> 6);
  const int lane = threadIdx.x & 63;
  const ush* rh = p2h + (size_t)col * HIDh;
  const ush* rl = p2l + (size_t)col * HIDh;
  float acc = 0.f;
#pragma unroll
  for (int ii = 0; ii < 64; ++ii) {
    int k = lane + ii * 64;
    acc += cv1[k] * (bf2f(rh[k]) + bf2f(rl[k]));
  }
#pragma unroll
  for (int off = 32; off; off >>= 1) acc += __shfl_xor(acc, off, 64);
  if (lane == 0) cv2[col] = acc + bp2[col];
}

static inline void launch_gemm6(const float* A, const ush* Bh, const ush* Bm,
                                const ush* Bl, const float* bias, float* C,
                                int M, int N, int K, bool gelu, int bn,
                                hipStream_t st)
{
  dim3 blk(256);
  if (bn == 128) {
    dim3 g(N / 128, M / 128);
    if (gelu) hipLaunchKernelGGL((gemm6_k<1,128>), g, blk, 0, st, A, Bh, Bm, Bl, bias, C, M, N, K);
    else      hipLaunchKernelGGL((gemm6_k<0,128>), g, blk, 0, st, A, Bh, Bm, Bl, bias, C, M, N, K);
  } else {
    dim3 g(N / 64, M / 128);
    if (gelu) hipLaunchKernelGGL((gemm6_k<1,64>), g, blk, 0, st, A, Bh, Bm, Bl, bias, C, M, N, K);
    else      hipLaunchKernelGGL((gemm6_k<0,64>), g, blk, 0, st, A, Bh, Bm, Bl, bias, C, M, N, K);
  }
}

extern "C" void kernel_launch(void* const* d_in, const int* in_sizes, int n_in,
                              void* d_out, int out_size, void* d_ws, size_t ws_size,
                              hipStream_t stream)
{
  const float* x     = (const float*)d_in[0];
  const float* masks = (const float*)d_in[1];
  const float* Wq  = (const float*)d_in[2];
  const float* bq  = (const float*)d_in[3];
  const float* Wk  = (const float*)d_in[4];
  const float* bk  = (const float*)d_in[5];
  const float* Wv  = (const float*)d_in[6];
  const float* bv  = (const float*)d_in[7];
  const float* Wo  = (const float*)d_in[8];
  const float* bo  = (const float*)d_in[9];
  const float* g1  = (const float*)d_in[10];
  const float* be1 = (const float*)d_in[11];
  const float* g2  = (const float*)d_in[12];
  const float* be2 = (const float*)d_in[13];
  const float* W1  = (const float*)d_in[14];
  const float* bf1 = (const float*)d_in[15];
  const float* W2  = (const float*)d_in[16];
  const float* bf2 = (const float*)d_in[17];
  const float* Wsp = (const float*)d_in[18];
  const float* bs  = (const float*)d_in[19];
  const float* P1  = (const float*)d_in[20];
  const float* bp1 = (const float*)d_in[21];
  const float* P2  = (const float*)d_in[22];
  const float* bp2 = (const float*)d_in[23];

  // ---- workspace: [W3 24M ush = 48MB][u0..u5 6x16.78MB][smalls] ≈ 148.9MB
  // W3: qkv h/m/l 3M each (0,3M,6M); Wo h/m/l (9M..12M); W1 (12M..18M);
  //     W2 (18M..24M).
  // pass1 (xin=x):  qkv=u0u1u2 ao=u3 t1=u4 hb=u5 ffh=u0u1 t1b=u4 feat1=u2
  // pass2 (xin=u2): qkv=u3u4u5 ao=u0 t1=u1 hb=u3 ffh=u4u5 t1b=u0 feat2=u1
  // post: pooled=u0, hid=u2..u5, p1 over W3[0..8M], p2 over d_ws[0..32M ush]
  //       (clobbers W3+p1+u0 — all dead by then).
  const size_t UW = (size_t)Dd * Dd;        // 1,048,576
  const size_t ND = (size_t)NTOK * Dd;      // 4,194,304 floats
  ush* w3 = (ush*)d_ws;
  ush *wqkvh = w3 + 0*UW, *wqkvm = w3 + 3*UW, *wqkvl = w3 + 6*UW;
  ush *woh = w3 + 9*UW,  *wom = w3 + 10*UW, *wol = w3 + 11*UW;
  ush *w1h = w3 + 12*UW, *w1m = w3 + 14*UW, *w1l = w3 + 16*UW;
  ush *w2h = w3 + 18*UW, *w2m = w3 + 20*UW, *w2l = w3 + 22*UW;
  float* ub = (float*)(w3 + 24*UW);
  float* u0 = ub + 0 * ND;
  float* u1 = ub + 1 * ND;
  float* u2 = ub + 2 * ND;
  float* u3 = ub + 3 * ND;
  float* u4 = ub + 4 * ND;
  float* u5 = ub + 5 * ND;
  float* sm = ub + 6 * ND;
  float* sbuf = sm;                  // NTOK
  float* svb  = sm + NTOK;           // NTOK
  int*   segb = (int*)(sm + 2 * NTOK);
  int*   nact = (int*)(sm + 3 * NTOK);           // 4 ints
  float* bqkv = sm + 3 * NTOK + 16;              // 3072
  float* cv1  = bqkv + QKVN;                     // 4096
  float* cv2  = cv1 + HIDh;                      // 4096

  float* pooled = u0;
  float* hid = u2;                   // spans u2..u5
  ush*   p1h = w3;                   // 4M ush
  ush*   p1l = w3 + 4*UW;
  ush*   p2h = (ush*)d_ws;           // 16M ush each plane
  ush*   p2l = p2h + (size_t)HIDh * HIDh;
  float* outp = (float*)d_out;
  float* nmask = outp + (size_t)NTOK * HIDh;

  // ---- weight prep ---------------------------------------------------------
  hipLaunchKernelGGL(wt3_k, dim3(Dd/32, Dd/32), dim3(256), 0, stream, Wq, wqkvh,        wqkvm,        wqkvl,        Dd, Dd);
  hipLaunchKernelGGL(wt3_k, dim3(Dd/32, Dd/32), dim3(256), 0, stream, Wk, wqkvh + UW,   wqkvm + UW,   wqkvl + UW,   Dd, Dd);
  hipLaunchKernelGGL(wt3_k, dim3(Dd/32, Dd/32), dim3(256), 0, stream, Wv, wqkvh + 2*UW, wqkvm + 2*UW, wqkvl + 2*UW, Dd, Dd);
  hipLaunchKernelGGL(wt3_k, dim3(Dd/32, Dd/32), dim3(256), 0, stream, Wo, woh, wom, wol, Dd, Dd);
  hipLaunchKernelGGL(wt3_k, dim3(FFf/32, Dd/32), dim3(256), 0, stream, W1, w1h, w1m, w1l, Dd, FFf);
  hipLaunchKernelGGL(wt3_k, dim3(Dd/32, FFf/32), dim3(256), 0, stream, W2, w2h, w2m, w2l, FFf, Dd);
  hipLaunchKernelGGL(bcat_k, dim3(QKVN/256), dim3(256), 0, stream, bq, bk, bv, bqkv);
  hipLaunchKernelGGL(cv1_k, dim3(HIDh/256), dim3(256), 0, stream, bp1, cv1);

  auto enc = [&](const float* xin, float* qkv, float* ao, float* t1, float* hb,
                 float* ffh, float* t1b, float* fout, int mode) {
    launch_gemm6(xin, wqkvh, wqkvm, wqkvl, bqkv, qkv, NTOK, QKVN, Dd, false, 128, stream);
    hipLaunchKernelGGL(attn_k, dim3(Bb * Hh, Ss / 64), dim3(256), 0, stream,
                       qkv, masks, ao, mode);
    launch_gemm6(ao, woh, wom, wol, bo, t1, NTOK, Dd, Dd, false, 64, stream);
    hipLaunchKernelGGL(ln_k, dim3(NTOK), dim3(256), 0, stream, t1, xin, g1, be1, hb);
    launch_gemm6(hb, w1h, w1m, w1l, bf1, ffh, NTOK, FFf, Dd, true, 128, stream);
    launch_gemm6(ffh, w2h, w2m, w2l, bf2, t1b, NTOK, Dd, FFf, false, 64, stream);
    hipLaunchKernelGGL(ln_k, dim3(NTOK), dim3(256), 0, stream, t1b, hb, g2, be2, fout);
  };

  // pass 1 (float mask ADDED): xin=x
  enc(x,  u0, u3, u4, u5, u0 /*ffh=u0u1*/, u4, u2 /*feat1*/, 0);
  // pass 2 (0/-1e9 mask): xin=u2
  enc(u2, u3, u0, u1, u3, u4 /*ffh=u4u5*/, u0, u1 /*feat2*/, 1);

  hipLaunchKernelGGL(score_k, dim3(NTOK / 4), dim3(256), 0, stream, u1, Wsp, bs, sbuf);
  hipLaunchKernelGGL(scan_k, dim3(Bb), dim3(256), 0, stream, sbuf, masks, svb, segb, nmask, nact);
  hipMemsetAsync(pooled, 0, ND * sizeof(float), stream);
  hipLaunchKernelGGL(scatter_k, dim3(NTOK), dim3(256), 0, stream, x, svb, segb, pooled);

  // projector (bf16x3 + inactive-block skip)
  hipLaunchKernelGGL(wt_k, dim3(HIDh / 32, Dd / 32), dim3(256), 0, stream, P1, p1h, p1l, Dd, HIDh);
  hipLaunchKernelGGL((gemm3s_k<1>), dim3(HIDh / 128, NTOK / 128), dim3(256), 0, stream,
                     pooled, p1h, p1l, bp1, hid, NTOK, HIDh, Dd, nact, cv1);
  hipLaunchKernelGGL(wt_k, dim3(HIDh / 32, HIDh / 32), dim3(256), 0, stream, P2, p2h, p2l, HIDh, HIDh);
  hipLaunchKernelGGL(cv2_k, dim3(HIDh / 4), dim3(256), 0, stream, cv1, p2h, p2l, bp2, cv2);
  hipLaunchKernelGGL((gemm3s_k<0>), dim3(HIDh / 128, NTOK / 128), dim3(256), 0, stream,
                     hid, p2h, p2l, bp2, outp, NTOK, HIDh, HIDh, nact, cv2);
}